// Round 14
// baseline (707.633 us; speedup 1.0000x reference)
//
#include <hip/hip_runtime.h>
#include <math.h>

typedef unsigned short u16;
typedef __bf16 bf16;
typedef bf16 bf16x8 __attribute__((ext_vector_type(8)));
typedef float f32x4 __attribute__((ext_vector_type(4)));
typedef u16 u16x8 __attribute__((ext_vector_type(8)));

__device__ inline float b2f(u16 u){ unsigned x = ((unsigned)u) << 16; return __builtin_bit_cast(float, x); }
__device__ inline u16 f2b(float f){ bf16 b = (bf16)f; return __builtin_bit_cast(u16, b); }
__device__ inline f32x4 mfma16(bf16x8 a, bf16x8 b, f32x4 c){
    return __builtin_amdgcn_mfma_f32_16x16x32_bf16(a, b, c, 0, 0, 0);
}
__device__ inline void unp8(uint4 v, float* f){
    f[0]=__builtin_bit_cast(float, v.x<<16); f[1]=__builtin_bit_cast(float, v.x&0xffff0000u);
    f[2]=__builtin_bit_cast(float, v.y<<16); f[3]=__builtin_bit_cast(float, v.y&0xffff0000u);
    f[4]=__builtin_bit_cast(float, v.z<<16); f[5]=__builtin_bit_cast(float, v.z&0xffff0000u);
    f[6]=__builtin_bit_cast(float, v.w<<16); f[7]=__builtin_bit_cast(float, v.w&0xffff0000u);
}

// ---------------------------------------------------------------------------
// Merged weight repack: 7 sets, OIDHW fp32 -> [tap][co][ci] bf16. grid (64,7)
// ---------------------------------------------------------------------------
struct Rep7 {
    const float* src[7];
    u16* dst[7];
    int co[7];
    int ci[7];
};
__global__ __launch_bounds__(256) void repack7_k(Rep7 a)
{
    int w = blockIdx.y;
    const float* src = a.src[w]; u16* dst = a.dst[w];
    int Co = a.co[w], Ci = a.ci[w];
    int tot = 27 * Co * Ci;
    for (int e = blockIdx.x * 256 + threadIdx.x; e < tot; e += gridDim.x * 256) {
        int ci = e % Ci; int t2 = e / Ci; int co = t2 % Co; int tp = t2 / Co;
        dst[e] = f2b(src[(size_t)(co * Ci + ci) * 27 + tp]);
    }
}

// ---------------------------------------------------------------------------
// MFMA implicit-GEMM conv3d / convT3d v5: 512 thr (8 waves, 4M x 2N),
// BM=128 x BN, K-panel CK per tap. Rotated prefetch (panel it+1 loads issue
// before panel it's MFMA block). XCD-swizzled mtile (gx divisible by 8).
// Fused BN partial stats in epilogue. grid: (M/128, Co/BN, ISCONV?1:8)
// ---------------------------------------------------------------------------
template<bool ISCONV, int CK, int BN>
__global__ __launch_bounds__(512) void conv_mfma3_k(
    const u16* __restrict__ in, const u16* __restrict__ wt,
    const float* __restrict__ bias, u16* __restrict__ out,
    float* __restrict__ pm, float* __restrict__ pv,
    int Ci, int Co, int Di, int Hi, int Wi,
    int ld, int lh, int lw, int Do, int Ho, int Wo)
{
    constexpr int NK = CK / 32;
    constexpr int NF = BN / 32;
    __shared__ u16 As[128][CK + 8];
    __shared__ u16 Bs[BN][CK + 8];
    const int tid = threadIdx.x;
    const int gx = gridDim.x;
    const int bxr = blockIdx.x;
    const int mtile = (bxr & 7) * (gx >> 3) + (bxr >> 3);   // XCD-grouped
    const int co0 = blockIdx.y * BN;
    int pd = 0, ph = 0, pw = 0;
    if (!ISCONV) { int bz = blockIdx.z; pd = bz >> 2; ph = (bz >> 1) & 1; pw = bz & 1; }

    const int arow = tid >> 2, seg = tid & 3;
    int xo, yo, zo, n;
    { int m = mtile * 128 + arow;
      xo = m & ((1 << lw) - 1); m >>= lw;
      yo = m & ((1 << lh) - 1); m >>= lh;
      zo = m & ((1 << ld) - 1); n = m >> ld; }
    const bool isb = arow < BN;

    const int wave = tid >> 6, lane = tid & 63;
    const int wm = wave >> 1, wn = wave & 1;
    const int fr = lane & 15, fs = lane >> 4;

    f32x4 acc[2][NF];
    #pragma unroll
    for (int mf = 0; mf < 2; ++mf)
        #pragma unroll
        for (int nf = 0; nf < NF; ++nf) acc[mf][nf] = f32x4{0,0,0,0};

    const int ntd = ISCONV ? 3 : pd + 1;
    const int nth = ISCONV ? 3 : ph + 1;
    const int ntw = ISCONV ? 3 : pw + 1;
    const int nck = Ci / CK;
    const int T = ntd * nth * ntw * nck;
    const size_t HiWi = (size_t)Hi * Wi;

    int pjd = 0, pjh = 0, pjw = 0, pck = 0;
    uint4 av[NK], bv[NK];

    auto load_panel = [&]() {
        int zi = ISCONV ? 2 * zo + pjd - 1 : zo + (pd ? pjd : 0);
        int wd = ISCONV ? pjd : (pd ? (pjd ? 0 : 2) : 1);
        int yi = ISCONV ? 2 * yo + pjh - 1 : yo + (ph ? pjh : 0);
        int wh = ISCONV ? pjh : (ph ? (pjh ? 0 : 2) : 1);
        int xi = ISCONV ? 2 * xo + pjw - 1 : xo + (pw ? pjw : 0);
        int ww = ISCONV ? pjw : (pw ? (pjw ? 0 : 2) : 1);
        bool va = ((unsigned)zi < (unsigned)Di) && ((unsigned)yi < (unsigned)Hi) &&
                  ((unsigned)xi < (unsigned)Wi);
        size_t abase = 0;
        if (va) abase = (((size_t)(n * Di + zi)) * HiWi + (size_t)yi * Wi + xi) * Ci
                      + (size_t)pck * CK;
        int widx = wd * 9 + wh * 3 + ww;
        size_t bbase = ((size_t)widx * Co + (co0 + arow)) * (size_t)Ci + (size_t)pck * CK;
        #pragma unroll
        for (int k = 0; k < NK; ++k) {
            int col = k * 32 + seg * 8;
            av[k] = va  ? *reinterpret_cast<const uint4*>(in + abase + col) : uint4{0,0,0,0};
            bv[k] = isb ? *reinterpret_cast<const uint4*>(wt + bbase + col) : uint4{0,0,0,0};
        }
        ++pck;
        if (pck == nck) { pck = 0; ++pjw;
            if (pjw == ntw) { pjw = 0; ++pjh;
                if (pjh == nth) { pjh = 0; ++pjd; } } }
    };

    load_panel();
    for (int it = 0; it < T; ++it) {
        __syncthreads();
        #pragma unroll
        for (int k = 0; k < NK; ++k) {
            *reinterpret_cast<uint4*>(&As[arow][k * 32 + seg * 8]) = av[k];
            if (isb) *reinterpret_cast<uint4*>(&Bs[arow][k * 32 + seg * 8]) = bv[k];
        }
        __syncthreads();
        if (it + 1 < T) load_panel();
        #pragma unroll
        for (int k = 0; k < NK; ++k) {
            bf16x8 a0 = *reinterpret_cast<const bf16x8*>(&As[wm * 32      + fr][k * 32 + fs * 8]);
            bf16x8 a1 = *reinterpret_cast<const bf16x8*>(&As[wm * 32 + 16 + fr][k * 32 + fs * 8]);
            #pragma unroll
            for (int nf = 0; nf < NF; ++nf) {
                bf16x8 b = *reinterpret_cast<const bf16x8*>(
                    &Bs[wn * (BN / 2) + nf * 16 + fr][k * 32 + fs * 8]);
                acc[0][nf] = mfma16(a0, b, acc[0][nf]);
                acc[1][nf] = mfma16(a1, b, acc[1][nf]);
            }
        }
    }

    float bi[NF], s[NF], q[NF];
    #pragma unroll
    for (int nf = 0; nf < NF; ++nf) {
        bi[nf] = bias[co0 + wn * (BN / 2) + nf * 16 + fr];
        s[nf] = 0.f; q[nf] = 0.f;
    }
    #pragma unroll
    for (int mf = 0; mf < 2; ++mf) {
        #pragma unroll
        for (int j = 0; j < 4; ++j) {
            int rm = mtile * 128 + wm * 32 + mf * 16 + fs * 4 + j;
            size_t vox;
            if (ISCONV) vox = (size_t)rm;
            else {
                int X = rm & ((1 << lw) - 1); int m2 = rm >> lw;
                int Y = m2 & ((1 << lh) - 1); m2 >>= lh;
                int Z = m2 & ((1 << ld) - 1); int nn = m2 >> ld;
                vox = (((size_t)(nn * Do + (2 * Z + pd))) * Ho + (2 * Y + ph)) * Wo + (2 * X + pw);
            }
            #pragma unroll
            for (int nf = 0; nf < NF; ++nf) {
                float f = acc[mf][nf][j] + bi[nf];
                out[vox * Co + (co0 + wn * (BN / 2) + nf * 16 + fr)] = f2b(f);
                s[nf] += f; q[nf] += f * f;
            }
        }
    }
    __syncthreads();
    float* bnS = reinterpret_cast<float*>(&As[0][0]);   // [BN][16]
    float* bnQ = bnS + BN * 16;
    #pragma unroll
    for (int nf = 0; nf < NF; ++nf) {
        int cl = wn * (BN / 2) + nf * 16 + fr;
        bnS[cl * 16 + wm * 4 + fs] = s[nf];
        bnQ[cl * 16 + wm * 4 + fs] = q[nf];
    }
    __syncthreads();
    if (tid < BN) {
        float S = 0.f, Q = 0.f;
        #pragma unroll
        for (int i = 0; i < 16; ++i) { S += bnS[tid * 16 + i]; Q += bnQ[tid * 16 + i]; }
        int p = blockIdx.x + gridDim.x * (blockIdx.y + gridDim.y * blockIdx.z);
        pm[(size_t)p * BN + tid] = S;
        pv[(size_t)p * BN + tid] = Q;
    }
}

// ---------------------------------------------------------------------------
// enc1 v3: weights via block-uniform global reads; outputs staged in LDS,
// coalesced copy-out; FUSED BN1 partial stats (post-rounding, deterministic).
// (2,1,16,256,256) fp32 -> (2,16,128,128,96) bf16 CL. grid (1024, 2)
// ---------------------------------------------------------------------------
__global__ __launch_bounds__(256) void enc1_k(
    const float* __restrict__ x, const float* __restrict__ w,
    const float* __restrict__ bias, u16* __restrict__ out,
    float* __restrict__ pm, float* __restrict__ pv)
{
    __shared__ uint4 smem[256 * 13];
    float* Xi = reinterpret_cast<float*>(smem);
    const int tid = threadIdx.x;
    int t = blockIdx.x;
    const int tx = t & 7; t >>= 3;
    const int ty = t & 15; t >>= 4;
    const int tz = t;
    const int n = blockIdx.y;
    const int z0 = tz * 2, y0 = ty * 8, x0 = tx * 16;
    for (int i = tid; i < 2244; i += 256) {
        int fz = i / 561; int r = i - fz * 561; int fy = r / 33; int fx = r - fy * 33;
        int zi = z0 - 1 + fz, yi = 2 * y0 - 1 + fy, xi = 2 * x0 - 1 + fx;
        float v = 0.f;
        if ((unsigned)zi < 16u && (unsigned)yi < 256u && (unsigned)xi < 256u)
            v = x[((size_t)(n * 16 + zi) * 256 + yi) * 256 + xi];
        Xi[i] = v;
    }
    __syncthreads();
    const int lx = tid & 15, ly = (tid >> 4) & 7, lz = tid >> 7;
    float iv[27];
    #pragma unroll
    for (int kd = 0; kd < 3; ++kd)
        #pragma unroll
        for (int kh = 0; kh < 3; ++kh)
            #pragma unroll
            for (int kw = 0; kw < 3; ++kw)
                iv[kd * 9 + kh * 3 + kw] = Xi[(lz + kd) * 561 + (2 * ly + kh) * 33 + (2 * lx + kw)];
    __syncthreads();
    #pragma unroll
    for (int og = 0; og < 12; ++og) {
        u16x8 pk;
        #pragma unroll
        for (int oo = 0; oo < 8; ++oo) {
            int o = og * 8 + oo;
            float a = bias[o];
            #pragma unroll
            for (int tp = 0; tp < 27; ++tp) a += iv[tp] * w[o * 27 + tp];
            pk[oo] = f2b(a);
        }
        smem[tid * 13 + og] = __builtin_bit_cast(uint4, pk);
    }
    __syncthreads();
    #pragma unroll
    for (int it = 0; it < 12; ++it) {
        int i = it * 256 + tid;
        int r = i / 192, j = i - r * 192;
        int rz = r >> 3, ry = r & 7;
        int v = r * 16 + j / 12, c8 = j % 12;
        uint4 val = smem[v * 13 + c8];
        size_t voxbase = ((size_t)(n * 16 + z0 + rz) * 128 + (y0 + ry)) * 128 + x0;
        *reinterpret_cast<uint4*>(out + voxbase * 96 + (size_t)j * 8) = val;
    }
    // fused BN1 partial stats: channel c = tid (<96), fixed t2 order
    if (tid < 96) {
        int c8 = tid >> 3, ce = tid & 7;
        float S = 0.f, Q = 0.f;
        for (int t2 = 0; t2 < 256; ++t2) {
            u16x8 pk = __builtin_bit_cast(u16x8, smem[t2 * 13 + c8]);
            float f = b2f(pk[ce]);
            S += f; Q += f * f;
        }
        int blk = blockIdx.x + gridDim.x * blockIdx.y;
        pm[(size_t)blk * 96 + tid] = S;
        pv[(size_t)blk * 96 + tid] = Q;
    }
}

// ---------------------------------------------------------------------------
// dec4 phase A (GEMM) with fused BN-apply+LReLU on A. grid 8192.
// ---------------------------------------------------------------------------
__global__ __launch_bounds__(256) void dec4g_k(
    const u16* __restrict__ in, const u16* __restrict__ wt4,
    const float* __restrict__ sc, const float* __restrict__ sb,
    float* __restrict__ P)
{
    __shared__ u16 As[64][120];
    __shared__ u16 Bs[32][120];
    const int tid = threadIdx.x;
    const int vox0 = blockIdx.x << 6;
    for (int i = tid; i < 384; i += 256) {
        int row = i / 12, seg = i - row * 12;
        uint4 v = {0,0,0,0};
        if (row < 27) v = *reinterpret_cast<const uint4*>(wt4 + row * 96 + seg * 8);
        *reinterpret_cast<uint4*>(&Bs[row][seg * 8]) = v;
    }
    for (int i = tid; i < 768; i += 256) {
        int row = i / 12, seg = i - row * 12;
        uint4 v = *reinterpret_cast<const uint4*>(in + (size_t)(vox0 + row) * 96 + seg * 8);
        float f[8]; unp8(v, f);
        int c0 = seg * 8;
        u16x8 pk;
        #pragma unroll
        for (int e = 0; e < 8; ++e) {
            float y = f[e] * sc[c0 + e] + sb[c0 + e];
            y = y >= 0.f ? y : 0.2f * y;
            pk[e] = f2b(y);
        }
        *reinterpret_cast<u16x8*>(&As[row][seg * 8]) = pk;
    }
    __syncthreads();
    const int wave = tid >> 6, lane = tid & 63;
    const int fr = lane & 15, fs = lane >> 4;
    f32x4 acc0 = {0,0,0,0}, acc1 = {0,0,0,0};
    #pragma unroll
    for (int kk = 0; kk < 3; ++kk) {
        bf16x8 a  = *reinterpret_cast<const bf16x8*>(&As[wave * 16 + fr][kk * 32 + fs * 8]);
        bf16x8 b0 = *reinterpret_cast<const bf16x8*>(&Bs[fr     ][kk * 32 + fs * 8]);
        bf16x8 b1 = *reinterpret_cast<const bf16x8*>(&Bs[16 + fr][kk * 32 + fs * 8]);
        acc0 = mfma16(a, b0, acc0);
        acc1 = mfma16(a, b1, acc1);
    }
    #pragma unroll
    for (int j = 0; j < 4; ++j) {
        int vox = vox0 + wave * 16 + fs * 4 + j;
        P[(size_t)vox * 32 + fr]      = acc0[j];
        P[(size_t)vox * 32 + 16 + fr] = acc1[j];
    }
}

// ---------------------------------------------------------------------------
// dec4 phase B (gather). grid (4096, 2).
// ---------------------------------------------------------------------------
__global__ __launch_bounds__(256) void dec4s_k(
    const float* __restrict__ P, const float* __restrict__ bias,
    float* __restrict__ out)
{
    __shared__ float Pl[180 * 33];
    const int tid = threadIdx.x;
    int b = blockIdx.x;
    const int tx = b & 15; b >>= 4;
    const int ty = b & 31; b >>= 5;
    const int tz = b;
    const int n = blockIdx.y;
    const int Z0 = tz * 2, Y0 = ty * 8, X0 = tx * 16;
    const int yi0 = Y0 >> 1, xi0 = X0 >> 1;
    for (int i = tid; i < 5760; i += 256) {
        int row = i >> 5, c = i & 31;
        int dz = row / 45; int r = row - dz * 45; int dy = r / 9; int dx = r - dy * 9;
        int zi = Z0 - 1 + dz, yi = yi0 + dy, xi = xi0 + dx;
        float v = 0.f;
        if (zi >= 0 && zi < 16 && yi < 128 && xi < 128)
            v = P[((size_t)((n * 16 + zi) * 128 + yi) * 128 + xi) * 32 + c];
        Pl[row * 33 + c] = v;
    }
    __syncthreads();
    const int lx = tid & 15, ly = (tid >> 4) & 7, lz = tid >> 7;
    float acc = bias[0];
    #pragma unroll
    for (int qd = 0; qd < 3; ++qd) {
        int t = Z0 + lz + qd - 1;
        if (t < 0 || t >= 16) continue;
        int dz = lz + qd;
        #pragma unroll
        for (int qh = 0; qh < 3; ++qh) {
            int u = ly + qh - 1;
            if (u & 1) continue;
            int dy = u >> 1;
            #pragma unroll
            for (int qw = 0; qw < 3; ++qw) {
                int v = lx + qw - 1;
                if (v & 1) continue;
                int dx = v >> 1;
                int widx = (2 - qd) * 9 + (2 - qh) * 3 + (2 - qw);
                acc += Pl[(dz * 45 + dy * 9 + dx) * 33 + widx];
            }
        }
    }
    out[((size_t)(n * 16 + Z0 + lz) * 256 + (Y0 + ly)) * 256 + (X0 + lx)] = acc;
}

// ---------------------------------------------------------------------------
// BN finalize kernels
// ---------------------------------------------------------------------------
__global__ __launch_bounds__(64) void bnfin_k(
    const float* __restrict__ pm, const float* __restrict__ pv,
    const float* __restrict__ g, const float* __restrict__ be,
    float* __restrict__ sc, float* __restrict__ sb, int C, int G, float invcnt)
{
    int c = blockIdx.x;
    float S = 0.f, Q = 0.f;
    for (int b = threadIdx.x; b < G; b += 64) { S += pm[b * C + c]; Q += pv[b * C + c]; }
    #pragma unroll
    for (int off = 32; off; off >>= 1) {
        S += __shfl_down(S, off, 64);
        Q += __shfl_down(Q, off, 64);
    }
    if (threadIdx.x == 0) {
        float m = S * invcnt;
        float v = Q * invcnt - m * m;
        float s = g[c] * rsqrtf(v + 1e-5f);
        sc[c] = s; sb[c] = be[c] - m * s;
    }
}

__global__ __launch_bounds__(64) void bnfin3_k(
    const float* __restrict__ pm, const float* __restrict__ pv,
    const float* __restrict__ g, const float* __restrict__ be,
    float* __restrict__ sc, float* __restrict__ sb,
    int C, int BNl, int gx, int gy, int gz, float invcnt)
{
    int c = blockIdx.x;
    int cog = c / BNl, cl = c % BNl;
    int tot = gx * gz;
    float S = 0.f, Q = 0.f;
    for (int i = threadIdx.x; i < tot; i += 64) {
        int bx = i % gx, bz = i / gx;
        int p = bx + gx * (cog + gy * bz);
        S += pm[(size_t)p * BNl + cl];
        Q += pv[(size_t)p * BNl + cl];
    }
    #pragma unroll
    for (int off = 32; off; off >>= 1) {
        S += __shfl_down(S, off, 64);
        Q += __shfl_down(Q, off, 64);
    }
    if (threadIdx.x == 0) {
        float m = S * invcnt;
        float v = Q * invcnt - m * m;
        float s = g[c] * rsqrtf(v + 1e-5f);
        sc[c] = s; sb[c] = be[c] - m * s;
    }
}

__global__ __launch_bounds__(256) void bnapply_k(
    u16* __restrict__ a, const float* __restrict__ sc, const float* __restrict__ sb,
    int C, unsigned total8)
{
    unsigned g = blockIdx.x * 256 + threadIdx.x;
    unsigned stride = gridDim.x * 256;
    int c0 = (int)((g * 8u) % (unsigned)C);
    float lsc[8], lsb[8];
    #pragma unroll
    for (int e = 0; e < 8; ++e) { lsc[e] = sc[c0 + e]; lsb[e] = sb[c0 + e]; }
    for (unsigned i = g; i < total8; i += stride) {
        uint4 v = *reinterpret_cast<const uint4*>(a + (size_t)i * 8);
        float f[8]; unp8(v, f);
        u16x8 pk;
        #pragma unroll
        for (int e = 0; e < 8; ++e) {
            float y = f[e] * lsc[e] + lsb[e];
            y = y >= 0.f ? y : 0.2f * y;
            pk[e] = f2b(y);
        }
        *reinterpret_cast<u16x8*>(a + (size_t)i * 8) = pk;
    }
}

// ---------------------------------------------------------------------------
// memprep / znorm / scores / softmax / zhat (verified, unchanged)
// ---------------------------------------------------------------------------
__global__ __launch_bounds__(256) void memprep_k(
    const float* __restrict__ mem, u16* __restrict__ memb, u16* __restrict__ memT,
    float* __restrict__ mnorm)
{
    int k = blockIdx.x, c = threadIdx.x;
    if (k >= 2000) { memT[(size_t)c * 2048 + k] = 0; return; }
    float v = mem[(size_t)k * 256 + c];
    u16 b = f2b(v);
    memb[(size_t)k * 256 + c] = b;
    memT[(size_t)c * 2048 + k] = b;
    float s = v * v;
    #pragma unroll
    for (int off = 32; off; off >>= 1) s += __shfl_down(s, off, 64);
    __shared__ float red[4];
    if ((c & 63) == 0) red[c >> 6] = s;
    __syncthreads();
    if (c == 0) mnorm[k] = sqrtf(red[0] + red[1] + red[2] + red[3]);
}

__global__ __launch_bounds__(64) void znorm_k(
    const u16* __restrict__ z, float* __restrict__ znorm)
{
    int m = blockIdx.x, l = threadIdx.x;
    ushort4 v = *reinterpret_cast<const ushort4*>(z + (size_t)m * 256 + l * 4);
    float a = b2f(v.x), b = b2f(v.y), cc = b2f(v.z), d = b2f(v.w);
    float s = a * a + b * b + cc * cc + d * d;
    #pragma unroll
    for (int off = 32; off; off >>= 1) s += __shfl_down(s, off, 64);
    if (l == 0) znorm[m] = sqrtf(s);
}

__global__ __launch_bounds__(256) void scores_mfma_k(
    const u16* __restrict__ z, const u16* __restrict__ memb,
    const float* __restrict__ znorm, const float* __restrict__ mnorm,
    float* __restrict__ scores)
{
    __shared__ u16 As[64][40];
    __shared__ u16 Bs[64][40];
    const int tid = threadIdx.x;
    const int m0 = blockIdx.x << 6, n0 = blockIdx.y << 6;
    const int arow = tid >> 2, seg = tid & 3;
    const bool bok = (n0 + arow) < 2000;
    const int wave = tid >> 6, lane = tid & 63;
    const int wm = wave >> 1, wn = wave & 1, fr = lane & 15, fs = lane >> 4;
    f32x4 acc00 = {0,0,0,0}, acc01 = {0,0,0,0}, acc10 = {0,0,0,0}, acc11 = {0,0,0,0};
    for (int k0 = 0; k0 < 256; k0 += 32) {
        uint4 avv = *reinterpret_cast<const uint4*>(z + (size_t)(m0 + arow) * 256 + k0 + seg * 8);
        uint4 bvv = {0,0,0,0};
        if (bok) bvv = *reinterpret_cast<const uint4*>(memb + (size_t)(n0 + arow) * 256 + k0 + seg * 8);
        __syncthreads();
        *reinterpret_cast<uint4*>(&As[arow][seg * 8]) = avv;
        *reinterpret_cast<uint4*>(&Bs[arow][seg * 8]) = bvv;
        __syncthreads();
        bf16x8 a0 = *reinterpret_cast<const bf16x8*>(&As[wm * 32      + fr][fs * 8]);
        bf16x8 a1 = *reinterpret_cast<const bf16x8*>(&As[wm * 32 + 16 + fr][fs * 8]);
        bf16x8 b0 = *reinterpret_cast<const bf16x8*>(&Bs[wn * 32      + fr][fs * 8]);
        bf16x8 b1 = *reinterpret_cast<const bf16x8*>(&Bs[wn * 32 + 16 + fr][fs * 8]);
        acc00 = mfma16(a0, b0, acc00);
        acc01 = mfma16(a0, b1, acc01);
        acc10 = mfma16(a1, b0, acc10);
        acc11 = mfma16(a1, b1, acc11);
    }
    const int c0 = n0 + wn * 32 + fr, c1 = c0 + 16;
    float mn0 = (c0 < 2000) ? mnorm[c0] : 1.f;
    float mn1 = (c1 < 2000) ? mnorm[c1] : 1.f;
    #pragma unroll
    for (int mi = 0; mi < 2; ++mi) {
        f32x4 aN0 = mi ? acc10 : acc00;
        f32x4 aN1 = mi ? acc11 : acc01;
        #pragma unroll
        for (int j = 0; j < 4; ++j) {
            int rm = m0 + wm * 32 + mi * 16 + fs * 4 + j;
            float zn = znorm[rm];
            if (c0 < 2000) scores[(size_t)rm * 2000 + c0] = aN0[j] / fmaxf(zn * mn0, 1e-8f);
            if (c1 < 2000) scores[(size_t)rm * 2000 + c1] = aN1[j] / fmaxf(zn * mn1, 1e-8f);
        }
    }
}

__global__ __launch_bounds__(256) void softmax2_k(
    float* __restrict__ w, u16* __restrict__ wb16)
{
    __shared__ float red[4];
    const int m = blockIdx.x, t = threadIdx.x;
    const bool act = t < 250;
    float v[8];
    if (act) {
        float4 p0 = *reinterpret_cast<const float4*>(w + (size_t)m * 2000 + t * 8);
        float4 p1 = *reinterpret_cast<const float4*>(w + (size_t)m * 2000 + t * 8 + 4);
        v[0]=p0.x; v[1]=p0.y; v[2]=p0.z; v[3]=p0.w;
        v[4]=p1.x; v[5]=p1.y; v[6]=p1.z; v[7]=p1.w;
    } else {
        for (int i = 0; i < 8; ++i) v[i] = -1e30f;
    }
    float mx = -1e30f;
    for (int i = 0; i < 8; ++i) mx = fmaxf(mx, v[i]);
    #pragma unroll
    for (int off = 32; off; off >>= 1) mx = fmaxf(mx, __shfl_down(mx, off, 64));
    if ((t & 63) == 0) red[t >> 6] = mx;
    __syncthreads();
    mx = fmaxf(fmaxf(red[0], red[1]), fmaxf(red[2], red[3]));
    __syncthreads();
    float e[8], sm = 0.f;
    for (int i = 0; i < 8; ++i) {
        e[i] = act ? expf(v[i] - mx) : 0.f;
        sm += e[i];
    }
    #pragma unroll
    for (int off = 32; off; off >>= 1) sm += __shfl_down(sm, off, 64);
    if ((t & 63) == 0) red[t >> 6] = sm;
    __syncthreads();
    float inv = 1.0f / (red[0] + red[1] + red[2] + red[3]);
    u16x8 pk = {0,0,0,0,0,0,0,0};
    if (act) {
        float r[8];
        for (int i = 0; i < 8; ++i) { r[i] = e[i] * inv; pk[i] = f2b(r[i]); }
        float4 o0, o1;
        o0.x=r[0]; o0.y=r[1]; o0.z=r[2]; o0.w=r[3];
        o1.x=r[4]; o1.y=r[5]; o1.z=r[6]; o1.w=r[7];
        *reinterpret_cast<float4*>(w + (size_t)m * 2000 + t * 8)     = o0;
        *reinterpret_cast<float4*>(w + (size_t)m * 2000 + t * 8 + 4) = o1;
    }
    *reinterpret_cast<u16x8*>(wb16 + (size_t)m * 2048 + t * 8) = pk;
}

__global__ __launch_bounds__(256) void zhat_mfma_k(
    const u16* __restrict__ wb16, const u16* __restrict__ memT,
    u16* __restrict__ zf)
{
    __shared__ u16 As[64][40];
    __shared__ u16 Bs[64][40];
    const int tid = threadIdx.x;
    const int m0 = blockIdx.x << 6, n0 = blockIdx.y << 6;
    const int arow = tid >> 2, seg = tid & 3;
    const int wave = tid >> 6, lane = tid & 63;
    const int wm = wave >> 1, wn = wave & 1, fr = lane & 15, fs = lane >> 4;
    f32x4 acc00 = {0,0,0,0}, acc01 = {0,0,0,0}, acc10 = {0,0,0,0}, acc11 = {0,0,0,0};
    for (int k0 = 0; k0 < 2048; k0 += 32) {
        uint4 avv = *reinterpret_cast<const uint4*>(wb16 + (size_t)(m0 + arow) * 2048 + k0 + seg * 8);
        uint4 bvv = *reinterpret_cast<const uint4*>(memT + (size_t)(n0 + arow) * 2048 + k0 + seg * 8);
        __syncthreads();
        *reinterpret_cast<uint4*>(&As[arow][seg * 8]) = avv;
        *reinterpret_cast<uint4*>(&Bs[arow][seg * 8]) = bvv;
        __syncthreads();
        bf16x8 a0 = *reinterpret_cast<const bf16x8*>(&As[wm * 32      + fr][fs * 8]);
        bf16x8 a1 = *reinterpret_cast<const bf16x8*>(&As[wm * 32 + 16 + fr][fs * 8]);
        bf16x8 b0 = *reinterpret_cast<const bf16x8*>(&Bs[wn * 32      + fr][fs * 8]);
        bf16x8 b1 = *reinterpret_cast<const bf16x8*>(&Bs[wn * 32 + 16 + fr][fs * 8]);
        acc00 = mfma16(a0, b0, acc00);
        acc01 = mfma16(a0, b1, acc01);
        acc10 = mfma16(a1, b0, acc10);
        acc11 = mfma16(a1, b1, acc11);
    }
    const int c0 = n0 + wn * 32 + fr, c1 = c0 + 16;
    #pragma unroll
    for (int mi = 0; mi < 2; ++mi) {
        f32x4 aN0 = mi ? acc10 : acc00;
        f32x4 aN1 = mi ? acc11 : acc01;
        #pragma unroll
        for (int j = 0; j < 4; ++j) {
            int rm = m0 + wm * 32 + mi * 16 + fs * 4 + j;
            zf[(size_t)rm * 256 + c0] = f2b(aN0[j]);
            zf[(size_t)rm * 256 + c1] = f2b(aN1[j]);
        }
    }
}

// ---------------------------------------------------------------------------
// launch
// ---------------------------------------------------------------------------
extern "C" void kernel_launch(void* const* d_in, const int* in_sizes, int n_in,
                              void* d_out, int out_size, void* d_ws, size_t ws_size,
                              hipStream_t stream)
{
    const float* x     = (const float*)d_in[0];
    const float* ew[4] = { (const float*)d_in[1],  (const float*)d_in[5],
                           (const float*)d_in[9],  (const float*)d_in[13] };
    const float* eb[4] = { (const float*)d_in[2],  (const float*)d_in[6],
                           (const float*)d_in[10], (const float*)d_in[14] };
    const float* eg[4] = { (const float*)d_in[3],  (const float*)d_in[7],
                           (const float*)d_in[11], (const float*)d_in[15] };
    const float* ebe[4]= { (const float*)d_in[4],  (const float*)d_in[8],
                           (const float*)d_in[12], (const float*)d_in[16] };
    const float* mem   = (const float*)d_in[17];
    const float* dw[4] = { (const float*)d_in[18], (const float*)d_in[22],
                           (const float*)d_in[26], (const float*)d_in[30] };
    const float* db[4] = { (const float*)d_in[19], (const float*)d_in[23],
                           (const float*)d_in[27], (const float*)d_in[31] };
    const float* dg[3] = { (const float*)d_in[20], (const float*)d_in[24],
                           (const float*)d_in[28] };
    const float* dbe[3]= { (const float*)d_in[21], (const float*)d_in[25],
                           (const float*)d_in[29] };

    float* outp  = (float*)d_out;
    float* w_out = (float*)d_out + 2097152;

    char* p = (char*)d_ws;
    auto take = [&](size_t bytes) -> char* {
        char* q = p; p += (bytes + 255) & ~(size_t)255; return q;
    };
    u16* b1   = (u16*)take(50331648ull * 2);
    u16* b2   = (u16*)take(8388608ull * 2);
    u16* b3   = (u16*)take(2097152ull * 2);
    u16* b4   = (u16*)take(262144ull * 2);
    u16* zf   = (u16*)take(262144ull * 2);
    u16* w2   = (u16*)take(331776ull * 2);
    u16* w3   = (u16*)take(884736ull * 2);
    u16* w4   = (u16*)take(1769472ull * 2);
    u16* wd1  = (u16*)take(1769472ull * 2);
    u16* wd2  = (u16*)take(884736ull * 2);
    u16* wd3  = (u16*)take(331776ull * 2);
    u16* wd4  = (u16*)take(2592ull * 2);
    u16* memb = (u16*)take(512000ull * 2);
    u16* memT = (u16*)take(524288ull * 2);
    u16* wb16 = (u16*)take(2097152ull * 2);
    float* P     = (float*)take(16777216ull * 4);
    float* pm    = (float*)take(1048576ull * 4);
    float* pv    = (float*)take(1048576ull * 4);
    float* scb   = (float*)take(7 * 512 * 4);
    float* mnorm = (float*)take(2048 * 4);
    float* znorm = (float*)take(1024 * 4);

    auto SC = [&](int l) { return scb + l * 512; };
    auto SB = [&](int l) { return scb + l * 512 + 256; };

    auto bnc = [&](u16* buf, const float* g, const float* be, int C, int BNl,
                   unsigned total8, int G, int gx, int gy, int gz, int slot, bool apply) {
        bnfin3_k<<<C, 64, 0, stream>>>(pm, pv, g, be, SC(slot), SB(slot),
                                       C, BNl, gx, gy, gz,
                                       (float)C / ((float)total8 * 8.0f));
        if (apply) bnapply_k<<<G, 256, 0, stream>>>(buf, SC(slot), SB(slot), C, total8);
    };

    // ---- weight + memory prep ----
    Rep7 ra;
    ra.src[0]=ew[1]; ra.dst[0]=w2;  ra.co[0]=128; ra.ci[0]=96;
    ra.src[1]=ew[2]; ra.dst[1]=w3;  ra.co[1]=256; ra.ci[1]=128;
    ra.src[2]=ew[3]; ra.dst[2]=w4;  ra.co[2]=256; ra.ci[2]=256;
    ra.src[3]=dw[0]; ra.dst[3]=wd1; ra.co[3]=256; ra.ci[3]=256;
    ra.src[4]=dw[1]; ra.dst[4]=wd2; ra.co[4]=128; ra.ci[4]=256;
    ra.src[5]=dw[2]; ra.dst[5]=wd3; ra.co[5]=96;  ra.ci[5]=128;
    ra.src[6]=dw[3]; ra.dst[6]=wd4; ra.co[6]=1;   ra.ci[6]=96;
    repack7_k<<<dim3(64, 7), 256, 0, stream>>>(ra);
    memprep_k<<<2048, 256, 0, stream>>>(mem, memb, memT, mnorm);

    // ---- encoder ----
    enc1_k<<<dim3(1024, 2), 256, 0, stream>>>(x, ew[0], eb[0], b1, pm, pv);
    bnfin_k<<<96, 64, 0, stream>>>(pm, pv, eg[0], ebe[0], SC(0), SB(0), 96, 2048,
                                   96.0f / (6291456.0f * 8.0f));
    bnapply_k<<<768, 256, 0, stream>>>(b1, SC(0), SB(0), 96, 6291456u);

    conv_mfma3_k<true, 96, 128><<<dim3(512, 1, 1), 512, 0, stream>>>(
        b1, w2, eb[1], b2, pm, pv, 96, 128, 16, 128, 128, 3, 6, 6, 8, 64, 64);
    bnc(b2, eg[1], ebe[1], 128, 128, 1048576u, 512, 512, 1, 1, 1, true);

    conv_mfma3_k<true, 128, 64><<<dim3(64, 4, 1), 512, 0, stream>>>(
        b2, w3, eb[2], b3, pm, pv, 128, 256, 8, 64, 64, 2, 5, 5, 4, 32, 32);
    bnc(b3, eg[2], ebe[2], 256, 64, 262144u, 512, 64, 4, 1, 2, true);

    conv_mfma3_k<true, 128, 64><<<dim3(8, 4, 1), 512, 0, stream>>>(
        b3, w4, eb[3], b4, pm, pv, 256, 256, 4, 32, 32, 1, 4, 4, 2, 16, 16);
    bnc(b4, eg[3], ebe[3], 256, 64, 32768u, 128, 8, 4, 1, 3, true);

    // ---- memory module ----
    znorm_k<<<1024, 64, 0, stream>>>(b4, znorm);
    scores_mfma_k<<<dim3(16, 32), 256, 0, stream>>>(b4, memb, znorm, mnorm, w_out);
    softmax2_k<<<1024, 256, 0, stream>>>(w_out, wb16);
    zhat_mfma_k<<<dim3(16, 4), 256, 0, stream>>>(wb16, memT, zf);

    // ---- decoder ----
    conv_mfma3_k<false, 128, 64><<<dim3(8, 4, 8), 512, 0, stream>>>(
        zf, wd1, db[0], b3, pm, pv, 256, 256, 2, 16, 16, 1, 4, 4, 4, 32, 32);
    bnc(b3, dg[0], dbe[0], 256, 64, 262144u, 512, 8, 4, 8, 4, true);

    conv_mfma3_k<false, 128, 64><<<dim3(64, 2, 8), 512, 0, stream>>>(
        b3, wd2, db[1], b2, pm, pv, 256, 128, 4, 32, 32, 2, 5, 5, 8, 64, 64);
    bnc(b2, dg[1], dbe[1], 128, 64, 1048576u, 512, 64, 2, 8, 5, true);

    conv_mfma3_k<false, 128, 96><<<dim3(512, 1, 8), 512, 0, stream>>>(
        b2, wd3, db[2], b1, pm, pv, 128, 96, 8, 64, 64, 3, 6, 6, 16, 128, 128);
    // BN7 fused into dec4g (reads raw b1 + SC(6)/SB(6)) — finalize only.
    bnc(b1, dg[2], dbe[2], 96, 96, 6291456u, 768, 512, 1, 8, 6, false);

    // ---- dec4: GEMM (fused BN7+LReLU on A) then tap-gather ----
    dec4g_k<<<8192, 256, 0, stream>>>(b1, wd4, SC(6), SB(6), P);
    dec4s_k<<<dim3(4096, 2), 256, 0, stream>>>(P, db[3], outp);
}

// Round 15
// 707.555 us; speedup vs baseline: 1.0001x; 1.0001x over previous
//
#include <hip/hip_runtime.h>
#include <math.h>

typedef unsigned short u16;
typedef __bf16 bf16;
typedef bf16 bf16x8 __attribute__((ext_vector_type(8)));
typedef float f32x4 __attribute__((ext_vector_type(4)));
typedef u16 u16x8 __attribute__((ext_vector_type(8)));

__device__ inline float b2f(u16 u){ unsigned x = ((unsigned)u) << 16; return __builtin_bit_cast(float, x); }
__device__ inline u16 f2b(float f){ bf16 b = (bf16)f; return __builtin_bit_cast(u16, b); }
__device__ inline f32x4 mfma16(bf16x8 a, bf16x8 b, f32x4 c){
    return __builtin_amdgcn_mfma_f32_16x16x32_bf16(a, b, c, 0, 0, 0);
}
__device__ inline void unp8(uint4 v, float* f){
    f[0]=__builtin_bit_cast(float, v.x<<16); f[1]=__builtin_bit_cast(float, v.x&0xffff0000u);
    f[2]=__builtin_bit_cast(float, v.y<<16); f[3]=__builtin_bit_cast(float, v.y&0xffff0000u);
    f[4]=__builtin_bit_cast(float, v.z<<16); f[5]=__builtin_bit_cast(float, v.z&0xffff0000u);
    f[6]=__builtin_bit_cast(float, v.w<<16); f[7]=__builtin_bit_cast(float, v.w&0xffff0000u);
}

// ---------------------------------------------------------------------------
// Merged weight repack: 7 sets, OIDHW fp32 -> [tap][co][ci] bf16. grid (64,7)
// ---------------------------------------------------------------------------
struct Rep7 {
    const float* src[7];
    u16* dst[7];
    int co[7];
    int ci[7];
};
__global__ __launch_bounds__(256) void repack7_k(Rep7 a)
{
    int w = blockIdx.y;
    const float* src = a.src[w]; u16* dst = a.dst[w];
    int Co = a.co[w], Ci = a.ci[w];
    int tot = 27 * Co * Ci;
    for (int e = blockIdx.x * 256 + threadIdx.x; e < tot; e += gridDim.x * 256) {
        int ci = e % Ci; int t2 = e / Ci; int co = t2 % Co; int tp = t2 / Co;
        dst[e] = f2b(src[(size_t)(co * Ci + ci) * 27 + tp]);
    }
}

// ---------------------------------------------------------------------------
// MFMA implicit-GEMM conv3d / convT3d v5: 512 thr (8 waves, 4M x 2N),
// BM=128 x BN, K-panel CK per tap. Rotated prefetch (panel it+1 loads issue
// before panel it's MFMA block). XCD-swizzled mtile (gx divisible by 8).
// Fused BN partial stats in epilogue. grid: (M/128, Co/BN, ISCONV?1:8)
// ---------------------------------------------------------------------------
template<bool ISCONV, int CK, int BN>
__global__ __launch_bounds__(512) void conv_mfma3_k(
    const u16* __restrict__ in, const u16* __restrict__ wt,
    const float* __restrict__ bias, u16* __restrict__ out,
    float* __restrict__ pm, float* __restrict__ pv,
    int Ci, int Co, int Di, int Hi, int Wi,
    int ld, int lh, int lw, int Do, int Ho, int Wo)
{
    constexpr int NK = CK / 32;
    constexpr int NF = BN / 32;
    __shared__ u16 As[128][CK + 8];
    __shared__ u16 Bs[BN][CK + 8];
    const int tid = threadIdx.x;
    const int gx = gridDim.x;
    const int bxr = blockIdx.x;
    const int mtile = (bxr & 7) * (gx >> 3) + (bxr >> 3);   // XCD-grouped
    const int co0 = blockIdx.y * BN;
    int pd = 0, ph = 0, pw = 0;
    if (!ISCONV) { int bz = blockIdx.z; pd = bz >> 2; ph = (bz >> 1) & 1; pw = bz & 1; }

    const int arow = tid >> 2, seg = tid & 3;
    int xo, yo, zo, n;
    { int m = mtile * 128 + arow;
      xo = m & ((1 << lw) - 1); m >>= lw;
      yo = m & ((1 << lh) - 1); m >>= lh;
      zo = m & ((1 << ld) - 1); n = m >> ld; }
    const bool isb = arow < BN;

    const int wave = tid >> 6, lane = tid & 63;
    const int wm = wave >> 1, wn = wave & 1;
    const int fr = lane & 15, fs = lane >> 4;

    f32x4 acc[2][NF];
    #pragma unroll
    for (int mf = 0; mf < 2; ++mf)
        #pragma unroll
        for (int nf = 0; nf < NF; ++nf) acc[mf][nf] = f32x4{0,0,0,0};

    const int ntd = ISCONV ? 3 : pd + 1;
    const int nth = ISCONV ? 3 : ph + 1;
    const int ntw = ISCONV ? 3 : pw + 1;
    const int nck = Ci / CK;
    const int T = ntd * nth * ntw * nck;
    const size_t HiWi = (size_t)Hi * Wi;

    int pjd = 0, pjh = 0, pjw = 0, pck = 0;
    uint4 av[NK], bv[NK];

    auto load_panel = [&]() {
        int zi = ISCONV ? 2 * zo + pjd - 1 : zo + (pd ? pjd : 0);
        int wd = ISCONV ? pjd : (pd ? (pjd ? 0 : 2) : 1);
        int yi = ISCONV ? 2 * yo + pjh - 1 : yo + (ph ? pjh : 0);
        int wh = ISCONV ? pjh : (ph ? (pjh ? 0 : 2) : 1);
        int xi = ISCONV ? 2 * xo + pjw - 1 : xo + (pw ? pjw : 0);
        int ww = ISCONV ? pjw : (pw ? (pjw ? 0 : 2) : 1);
        bool va = ((unsigned)zi < (unsigned)Di) && ((unsigned)yi < (unsigned)Hi) &&
                  ((unsigned)xi < (unsigned)Wi);
        size_t abase = 0;
        if (va) abase = (((size_t)(n * Di + zi)) * HiWi + (size_t)yi * Wi + xi) * Ci
                      + (size_t)pck * CK;
        int widx = wd * 9 + wh * 3 + ww;
        size_t bbase = ((size_t)widx * Co + (co0 + arow)) * (size_t)Ci + (size_t)pck * CK;
        #pragma unroll
        for (int k = 0; k < NK; ++k) {
            int col = k * 32 + seg * 8;
            av[k] = va  ? *reinterpret_cast<const uint4*>(in + abase + col) : uint4{0,0,0,0};
            bv[k] = isb ? *reinterpret_cast<const uint4*>(wt + bbase + col) : uint4{0,0,0,0};
        }
        ++pck;
        if (pck == nck) { pck = 0; ++pjw;
            if (pjw == ntw) { pjw = 0; ++pjh;
                if (pjh == nth) { pjh = 0; ++pjd; } } }
    };

    load_panel();
    for (int it = 0; it < T; ++it) {
        __syncthreads();
        #pragma unroll
        for (int k = 0; k < NK; ++k) {
            *reinterpret_cast<uint4*>(&As[arow][k * 32 + seg * 8]) = av[k];
            if (isb) *reinterpret_cast<uint4*>(&Bs[arow][k * 32 + seg * 8]) = bv[k];
        }
        __syncthreads();
        if (it + 1 < T) load_panel();
        #pragma unroll
        for (int k = 0; k < NK; ++k) {
            bf16x8 a0 = *reinterpret_cast<const bf16x8*>(&As[wm * 32      + fr][k * 32 + fs * 8]);
            bf16x8 a1 = *reinterpret_cast<const bf16x8*>(&As[wm * 32 + 16 + fr][k * 32 + fs * 8]);
            #pragma unroll
            for (int nf = 0; nf < NF; ++nf) {
                bf16x8 b = *reinterpret_cast<const bf16x8*>(
                    &Bs[wn * (BN / 2) + nf * 16 + fr][k * 32 + fs * 8]);
                acc[0][nf] = mfma16(a0, b, acc[0][nf]);
                acc[1][nf] = mfma16(a1, b, acc[1][nf]);
            }
        }
    }

    float bi[NF], s[NF], q[NF];
    #pragma unroll
    for (int nf = 0; nf < NF; ++nf) {
        bi[nf] = bias[co0 + wn * (BN / 2) + nf * 16 + fr];
        s[nf] = 0.f; q[nf] = 0.f;
    }
    #pragma unroll
    for (int mf = 0; mf < 2; ++mf) {
        #pragma unroll
        for (int j = 0; j < 4; ++j) {
            int rm = mtile * 128 + wm * 32 + mf * 16 + fs * 4 + j;
            size_t vox;
            if (ISCONV) vox = (size_t)rm;
            else {
                int X = rm & ((1 << lw) - 1); int m2 = rm >> lw;
                int Y = m2 & ((1 << lh) - 1); m2 >>= lh;
                int Z = m2 & ((1 << ld) - 1); int nn = m2 >> ld;
                vox = (((size_t)(nn * Do + (2 * Z + pd))) * Ho + (2 * Y + ph)) * Wo + (2 * X + pw);
            }
            #pragma unroll
            for (int nf = 0; nf < NF; ++nf) {
                float f = acc[mf][nf][j] + bi[nf];
                out[vox * Co + (co0 + wn * (BN / 2) + nf * 16 + fr)] = f2b(f);
                s[nf] += f; q[nf] += f * f;
            }
        }
    }
    __syncthreads();
    float* bnS = reinterpret_cast<float*>(&As[0][0]);   // [BN][16]
    float* bnQ = bnS + BN * 16;
    #pragma unroll
    for (int nf = 0; nf < NF; ++nf) {
        int cl = wn * (BN / 2) + nf * 16 + fr;
        bnS[cl * 16 + wm * 4 + fs] = s[nf];
        bnQ[cl * 16 + wm * 4 + fs] = q[nf];
    }
    __syncthreads();
    if (tid < BN) {
        float S = 0.f, Q = 0.f;
        #pragma unroll
        for (int i = 0; i < 16; ++i) { S += bnS[tid * 16 + i]; Q += bnQ[tid * 16 + i]; }
        int p = blockIdx.x + gridDim.x * (blockIdx.y + gridDim.y * blockIdx.z);
        pm[(size_t)p * BN + tid] = S;
        pv[(size_t)p * BN + tid] = Q;
    }
}

// ---------------------------------------------------------------------------
// enc1 v2 (round-13 proven): weights via block-uniform global reads,
// outputs staged in LDS, coalesced copy-out. grid (1024, 2)
// ---------------------------------------------------------------------------
__global__ __launch_bounds__(256) void enc1_k(
    const float* __restrict__ x, const float* __restrict__ w,
    const float* __restrict__ bias, u16* __restrict__ out)
{
    __shared__ uint4 smem[256 * 13];
    float* Xi = reinterpret_cast<float*>(smem);
    const int tid = threadIdx.x;
    int t = blockIdx.x;
    const int tx = t & 7; t >>= 3;
    const int ty = t & 15; t >>= 4;
    const int tz = t;
    const int n = blockIdx.y;
    const int z0 = tz * 2, y0 = ty * 8, x0 = tx * 16;
    for (int i = tid; i < 2244; i += 256) {
        int fz = i / 561; int r = i - fz * 561; int fy = r / 33; int fx = r - fy * 33;
        int zi = z0 - 1 + fz, yi = 2 * y0 - 1 + fy, xi = 2 * x0 - 1 + fx;
        float v = 0.f;
        if ((unsigned)zi < 16u && (unsigned)yi < 256u && (unsigned)xi < 256u)
            v = x[((size_t)(n * 16 + zi) * 256 + yi) * 256 + xi];
        Xi[i] = v;
    }
    __syncthreads();
    const int lx = tid & 15, ly = (tid >> 4) & 7, lz = tid >> 7;
    float iv[27];
    #pragma unroll
    for (int kd = 0; kd < 3; ++kd)
        #pragma unroll
        for (int kh = 0; kh < 3; ++kh)
            #pragma unroll
            for (int kw = 0; kw < 3; ++kw)
                iv[kd * 9 + kh * 3 + kw] = Xi[(lz + kd) * 561 + (2 * ly + kh) * 33 + (2 * lx + kw)];
    __syncthreads();
    #pragma unroll
    for (int og = 0; og < 12; ++og) {
        u16x8 pk;
        #pragma unroll
        for (int oo = 0; oo < 8; ++oo) {
            int o = og * 8 + oo;
            float a = bias[o];
            #pragma unroll
            for (int tp = 0; tp < 27; ++tp) a += iv[tp] * w[o * 27 + tp];
            pk[oo] = f2b(a);
        }
        smem[tid * 13 + og] = __builtin_bit_cast(uint4, pk);
    }
    __syncthreads();
    #pragma unroll
    for (int it = 0; it < 12; ++it) {
        int i = it * 256 + tid;
        int r = i / 192, j = i - r * 192;
        int rz = r >> 3, ry = r & 7;
        int v = r * 16 + j / 12, c8 = j % 12;
        uint4 val = smem[v * 13 + c8];
        size_t voxbase = ((size_t)(n * 16 + z0 + rz) * 128 + (y0 + ry)) * 128 + x0;
        *reinterpret_cast<uint4*>(out + voxbase * 96 + (size_t)j * 8) = val;
    }
}

// ---------------------------------------------------------------------------
// dec4 phase A (GEMM) with fused BN-apply+LReLU on A. grid 8192.
// ---------------------------------------------------------------------------
__global__ __launch_bounds__(256) void dec4g_k(
    const u16* __restrict__ in, const u16* __restrict__ wt4,
    const float* __restrict__ sc, const float* __restrict__ sb,
    float* __restrict__ P)
{
    __shared__ u16 As[64][120];
    __shared__ u16 Bs[32][120];
    const int tid = threadIdx.x;
    const int vox0 = blockIdx.x << 6;
    for (int i = tid; i < 384; i += 256) {
        int row = i / 12, seg = i - row * 12;
        uint4 v = {0,0,0,0};
        if (row < 27) v = *reinterpret_cast<const uint4*>(wt4 + row * 96 + seg * 8);
        *reinterpret_cast<uint4*>(&Bs[row][seg * 8]) = v;
    }
    for (int i = tid; i < 768; i += 256) {
        int row = i / 12, seg = i - row * 12;
        uint4 v = *reinterpret_cast<const uint4*>(in + (size_t)(vox0 + row) * 96 + seg * 8);
        float f[8]; unp8(v, f);
        int c0 = seg * 8;
        u16x8 pk;
        #pragma unroll
        for (int e = 0; e < 8; ++e) {
            float y = f[e] * sc[c0 + e] + sb[c0 + e];
            y = y >= 0.f ? y : 0.2f * y;
            pk[e] = f2b(y);
        }
        *reinterpret_cast<u16x8*>(&As[row][seg * 8]) = pk;
    }
    __syncthreads();
    const int wave = tid >> 6, lane = tid & 63;
    const int fr = lane & 15, fs = lane >> 4;
    f32x4 acc0 = {0,0,0,0}, acc1 = {0,0,0,0};
    #pragma unroll
    for (int kk = 0; kk < 3; ++kk) {
        bf16x8 a  = *reinterpret_cast<const bf16x8*>(&As[wave * 16 + fr][kk * 32 + fs * 8]);
        bf16x8 b0 = *reinterpret_cast<const bf16x8*>(&Bs[fr     ][kk * 32 + fs * 8]);
        bf16x8 b1 = *reinterpret_cast<const bf16x8*>(&Bs[16 + fr][kk * 32 + fs * 8]);
        acc0 = mfma16(a, b0, acc0);
        acc1 = mfma16(a, b1, acc1);
    }
    #pragma unroll
    for (int j = 0; j < 4; ++j) {
        int vox = vox0 + wave * 16 + fs * 4 + j;
        P[(size_t)vox * 32 + fr]      = acc0[j];
        P[(size_t)vox * 32 + 16 + fr] = acc1[j];
    }
}

// ---------------------------------------------------------------------------
// dec4 phase B (gather). grid (4096, 2).
// ---------------------------------------------------------------------------
__global__ __launch_bounds__(256) void dec4s_k(
    const float* __restrict__ P, const float* __restrict__ bias,
    float* __restrict__ out)
{
    __shared__ float Pl[180 * 33];
    const int tid = threadIdx.x;
    int b = blockIdx.x;
    const int tx = b & 15; b >>= 4;
    const int ty = b & 31; b >>= 5;
    const int tz = b;
    const int n = blockIdx.y;
    const int Z0 = tz * 2, Y0 = ty * 8, X0 = tx * 16;
    const int yi0 = Y0 >> 1, xi0 = X0 >> 1;
    for (int i = tid; i < 5760; i += 256) {
        int row = i >> 5, c = i & 31;
        int dz = row / 45; int r = row - dz * 45; int dy = r / 9; int dx = r - dy * 9;
        int zi = Z0 - 1 + dz, yi = yi0 + dy, xi = xi0 + dx;
        float v = 0.f;
        if (zi >= 0 && zi < 16 && yi < 128 && xi < 128)
            v = P[((size_t)((n * 16 + zi) * 128 + yi) * 128 + xi) * 32 + c];
        Pl[row * 33 + c] = v;
    }
    __syncthreads();
    const int lx = tid & 15, ly = (tid >> 4) & 7, lz = tid >> 7;
    float acc = bias[0];
    #pragma unroll
    for (int qd = 0; qd < 3; ++qd) {
        int t = Z0 + lz + qd - 1;
        if (t < 0 || t >= 16) continue;
        int dz = lz + qd;
        #pragma unroll
        for (int qh = 0; qh < 3; ++qh) {
            int u = ly + qh - 1;
            if (u & 1) continue;
            int dy = u >> 1;
            #pragma unroll
            for (int qw = 0; qw < 3; ++qw) {
                int v = lx + qw - 1;
                if (v & 1) continue;
                int dx = v >> 1;
                int widx = (2 - qd) * 9 + (2 - qh) * 3 + (2 - qw);
                acc += Pl[(dz * 45 + dy * 9 + dx) * 33 + widx];
            }
        }
    }
    out[((size_t)(n * 16 + Z0 + lz) * 256 + (Y0 + ly)) * 256 + (X0 + lx)] = acc;
}

// ---------------------------------------------------------------------------
// BN stats for enc1 output (deterministic two-stage LDS reduction).
// ---------------------------------------------------------------------------
__global__ __launch_bounds__(256) void bnstat_k(
    const u16* __restrict__ a, float* __restrict__ pm, float* __restrict__ pv,
    int C, unsigned total8)
{
    __shared__ float sS[256][8];
    __shared__ float sQ[256][8];
    unsigned g = blockIdx.x * 256 + threadIdx.x;
    unsigned stride = gridDim.x * 256;
    float s[8] = {0,0,0,0,0,0,0,0}, q[8] = {0,0,0,0,0,0,0,0};
    for (unsigned i = g; i < total8; i += stride) {
        uint4 v = *reinterpret_cast<const uint4*>(a + (size_t)i * 8);
        float f[8]; unp8(v, f);
        #pragma unroll
        for (int e = 0; e < 8; ++e) { s[e] += f[e]; q[e] += f[e] * f[e]; }
    }
    #pragma unroll
    for (int e = 0; e < 8; ++e) { sS[threadIdx.x][e] = s[e]; sQ[threadIdx.x][e] = q[e]; }
    __syncthreads();
    int c = threadIdx.x;
    if (c < C) {
        int C8 = C >> 3;
        int B = (int)((blockIdx.x * 2048u) % (unsigned)C);
        int r = c - B; r %= C; if (r < 0) r += C;
        int e = r & 7, t0 = r >> 3;
        float S = 0.f, Q = 0.f;
        for (int tt = t0; tt < 256; tt += C8) { S += sS[tt][e]; Q += sQ[tt][e]; }
        pm[blockIdx.x * C + c] = S;
        pv[blockIdx.x * C + c] = Q;
    }
}

__global__ __launch_bounds__(64) void bnfin_k(
    const float* __restrict__ pm, const float* __restrict__ pv,
    const float* __restrict__ g, const float* __restrict__ be,
    float* __restrict__ sc, float* __restrict__ sb, int C, int G, float invcnt)
{
    int c = blockIdx.x;
    float S = 0.f, Q = 0.f;
    for (int b = threadIdx.x; b < G; b += 64) { S += pm[b * C + c]; Q += pv[b * C + c]; }
    #pragma unroll
    for (int off = 32; off; off >>= 1) {
        S += __shfl_down(S, off, 64);
        Q += __shfl_down(Q, off, 64);
    }
    if (threadIdx.x == 0) {
        float m = S * invcnt;
        float v = Q * invcnt - m * m;
        float s = g[c] * rsqrtf(v + 1e-5f);
        sc[c] = s; sb[c] = be[c] - m * s;
    }
}

__global__ __launch_bounds__(64) void bnfin3_k(
    const float* __restrict__ pm, const float* __restrict__ pv,
    const float* __restrict__ g, const float* __restrict__ be,
    float* __restrict__ sc, float* __restrict__ sb,
    int C, int BNl, int gx, int gy, int gz, float invcnt)
{
    int c = blockIdx.x;
    int cog = c / BNl, cl = c % BNl;
    int tot = gx * gz;
    float S = 0.f, Q = 0.f;
    for (int i = threadIdx.x; i < tot; i += 64) {
        int bx = i % gx, bz = i / gx;
        int p = bx + gx * (cog + gy * bz);
        S += pm[(size_t)p * BNl + cl];
        Q += pv[(size_t)p * BNl + cl];
    }
    #pragma unroll
    for (int off = 32; off; off >>= 1) {
        S += __shfl_down(S, off, 64);
        Q += __shfl_down(Q, off, 64);
    }
    if (threadIdx.x == 0) {
        float m = S * invcnt;
        float v = Q * invcnt - m * m;
        float s = g[c] * rsqrtf(v + 1e-5f);
        sc[c] = s; sb[c] = be[c] - m * s;
    }
}

__global__ __launch_bounds__(256) void bnapply_k(
    u16* __restrict__ a, const float* __restrict__ sc, const float* __restrict__ sb,
    int C, unsigned total8)
{
    unsigned g = blockIdx.x * 256 + threadIdx.x;
    unsigned stride = gridDim.x * 256;
    int c0 = (int)((g * 8u) % (unsigned)C);
    float lsc[8], lsb[8];
    #pragma unroll
    for (int e = 0; e < 8; ++e) { lsc[e] = sc[c0 + e]; lsb[e] = sb[c0 + e]; }
    for (unsigned i = g; i < total8; i += stride) {
        uint4 v = *reinterpret_cast<const uint4*>(a + (size_t)i * 8);
        float f[8]; unp8(v, f);
        u16x8 pk;
        #pragma unroll
        for (int e = 0; e < 8; ++e) {
            float y = f[e] * lsc[e] + lsb[e];
            y = y >= 0.f ? y : 0.2f * y;
            pk[e] = f2b(y);
        }
        *reinterpret_cast<u16x8*>(a + (size_t)i * 8) = pk;
    }
}

// ---------------------------------------------------------------------------
// memprep / znorm / scores / softmax / zhat (verified, unchanged)
// ---------------------------------------------------------------------------
__global__ __launch_bounds__(256) void memprep_k(
    const float* __restrict__ mem, u16* __restrict__ memb, u16* __restrict__ memT,
    float* __restrict__ mnorm)
{
    int k = blockIdx.x, c = threadIdx.x;
    if (k >= 2000) { memT[(size_t)c * 2048 + k] = 0; return; }
    float v = mem[(size_t)k * 256 + c];
    u16 b = f2b(v);
    memb[(size_t)k * 256 + c] = b;
    memT[(size_t)c * 2048 + k] = b;
    float s = v * v;
    #pragma unroll
    for (int off = 32; off; off >>= 1) s += __shfl_down(s, off, 64);
    __shared__ float red[4];
    if ((c & 63) == 0) red[c >> 6] = s;
    __syncthreads();
    if (c == 0) mnorm[k] = sqrtf(red[0] + red[1] + red[2] + red[3]);
}

__global__ __launch_bounds__(64) void znorm_k(
    const u16* __restrict__ z, float* __restrict__ znorm)
{
    int m = blockIdx.x, l = threadIdx.x;
    ushort4 v = *reinterpret_cast<const ushort4*>(z + (size_t)m * 256 + l * 4);
    float a = b2f(v.x), b = b2f(v.y), cc = b2f(v.z), d = b2f(v.w);
    float s = a * a + b * b + cc * cc + d * d;
    #pragma unroll
    for (int off = 32; off; off >>= 1) s += __shfl_down(s, off, 64);
    if (l == 0) znorm[m] = sqrtf(s);
}

__global__ __launch_bounds__(256) void scores_mfma_k(
    const u16* __restrict__ z, const u16* __restrict__ memb,
    const float* __restrict__ znorm, const float* __restrict__ mnorm,
    float* __restrict__ scores)
{
    __shared__ u16 As[64][40];
    __shared__ u16 Bs[64][40];
    const int tid = threadIdx.x;
    const int m0 = blockIdx.x << 6, n0 = blockIdx.y << 6;
    const int arow = tid >> 2, seg = tid & 3;
    const bool bok = (n0 + arow) < 2000;
    const int wave = tid >> 6, lane = tid & 63;
    const int wm = wave >> 1, wn = wave & 1, fr = lane & 15, fs = lane >> 4;
    f32x4 acc00 = {0,0,0,0}, acc01 = {0,0,0,0}, acc10 = {0,0,0,0}, acc11 = {0,0,0,0};
    for (int k0 = 0; k0 < 256; k0 += 32) {
        uint4 avv = *reinterpret_cast<const uint4*>(z + (size_t)(m0 + arow) * 256 + k0 + seg * 8);
        uint4 bvv = {0,0,0,0};
        if (bok) bvv = *reinterpret_cast<const uint4*>(memb + (size_t)(n0 + arow) * 256 + k0 + seg * 8);
        __syncthreads();
        *reinterpret_cast<uint4*>(&As[arow][seg * 8]) = avv;
        *reinterpret_cast<uint4*>(&Bs[arow][seg * 8]) = bvv;
        __syncthreads();
        bf16x8 a0 = *reinterpret_cast<const bf16x8*>(&As[wm * 32      + fr][fs * 8]);
        bf16x8 a1 = *reinterpret_cast<const bf16x8*>(&As[wm * 32 + 16 + fr][fs * 8]);
        bf16x8 b0 = *reinterpret_cast<const bf16x8*>(&Bs[wn * 32      + fr][fs * 8]);
        bf16x8 b1 = *reinterpret_cast<const bf16x8*>(&Bs[wn * 32 + 16 + fr][fs * 8]);
        acc00 = mfma16(a0, b0, acc00);
        acc01 = mfma16(a0, b1, acc01);
        acc10 = mfma16(a1, b0, acc10);
        acc11 = mfma16(a1, b1, acc11);
    }
    const int c0 = n0 + wn * 32 + fr, c1 = c0 + 16;
    float mn0 = (c0 < 2000) ? mnorm[c0] : 1.f;
    float mn1 = (c1 < 2000) ? mnorm[c1] : 1.f;
    #pragma unroll
    for (int mi = 0; mi < 2; ++mi) {
        f32x4 aN0 = mi ? acc10 : acc00;
        f32x4 aN1 = mi ? acc11 : acc01;
        #pragma unroll
        for (int j = 0; j < 4; ++j) {
            int rm = m0 + wm * 32 + mi * 16 + fs * 4 + j;
            float zn = znorm[rm];
            if (c0 < 2000) scores[(size_t)rm * 2000 + c0] = aN0[j] / fmaxf(zn * mn0, 1e-8f);
            if (c1 < 2000) scores[(size_t)rm * 2000 + c1] = aN1[j] / fmaxf(zn * mn1, 1e-8f);
        }
    }
}

__global__ __launch_bounds__(256) void softmax2_k(
    float* __restrict__ w, u16* __restrict__ wb16)
{
    __shared__ float red[4];
    const int m = blockIdx.x, t = threadIdx.x;
    const bool act = t < 250;
    float v[8];
    if (act) {
        float4 p0 = *reinterpret_cast<const float4*>(w + (size_t)m * 2000 + t * 8);
        float4 p1 = *reinterpret_cast<const float4*>(w + (size_t)m * 2000 + t * 8 + 4);
        v[0]=p0.x; v[1]=p0.y; v[2]=p0.z; v[3]=p0.w;
        v[4]=p1.x; v[5]=p1.y; v[6]=p1.z; v[7]=p1.w;
    } else {
        for (int i = 0; i < 8; ++i) v[i] = -1e30f;
    }
    float mx = -1e30f;
    for (int i = 0; i < 8; ++i) mx = fmaxf(mx, v[i]);
    #pragma unroll
    for (int off = 32; off; off >>= 1) mx = fmaxf(mx, __shfl_down(mx, off, 64));
    if ((t & 63) == 0) red[t >> 6] = mx;
    __syncthreads();
    mx = fmaxf(fmaxf(red[0], red[1]), fmaxf(red[2], red[3]));
    __syncthreads();
    float e[8], sm = 0.f;
    for (int i = 0; i < 8; ++i) {
        e[i] = act ? expf(v[i] - mx) : 0.f;
        sm += e[i];
    }
    #pragma unroll
    for (int off = 32; off; off >>= 1) sm += __shfl_down(sm, off, 64);
    if ((t & 63) == 0) red[t >> 6] = sm;
    __syncthreads();
    float inv = 1.0f / (red[0] + red[1] + red[2] + red[3]);
    u16x8 pk = {0,0,0,0,0,0,0,0};
    if (act) {
        float r[8];
        for (int i = 0; i < 8; ++i) { r[i] = e[i] * inv; pk[i] = f2b(r[i]); }
        float4 o0, o1;
        o0.x=r[0]; o0.y=r[1]; o0.z=r[2]; o0.w=r[3];
        o1.x=r[4]; o1.y=r[5]; o1.z=r[6]; o1.w=r[7];
        *reinterpret_cast<float4*>(w + (size_t)m * 2000 + t * 8)     = o0;
        *reinterpret_cast<float4*>(w + (size_t)m * 2000 + t * 8 + 4) = o1;
    }
    *reinterpret_cast<u16x8*>(wb16 + (size_t)m * 2048 + t * 8) = pk;
}

__global__ __launch_bounds__(256) void zhat_mfma_k(
    const u16* __restrict__ wb16, const u16* __restrict__ memT,
    u16* __restrict__ zf)
{
    __shared__ u16 As[64][40];
    __shared__ u16 Bs[64][40];
    const int tid = threadIdx.x;
    const int m0 = blockIdx.x << 6, n0 = blockIdx.y << 6;
    const int arow = tid >> 2, seg = tid & 3;
    const int wave = tid >> 6, lane = tid & 63;
    const int wm = wave >> 1, wn = wave & 1, fr = lane & 15, fs = lane >> 4;
    f32x4 acc00 = {0,0,0,0}, acc01 = {0,0,0,0}, acc10 = {0,0,0,0}, acc11 = {0,0,0,0};
    for (int k0 = 0; k0 < 2048; k0 += 32) {
        uint4 avv = *reinterpret_cast<const uint4*>(wb16 + (size_t)(m0 + arow) * 2048 + k0 + seg * 8);
        uint4 bvv = *reinterpret_cast<const uint4*>(memT + (size_t)(n0 + arow) * 2048 + k0 + seg * 8);
        __syncthreads();
        *reinterpret_cast<uint4*>(&As[arow][seg * 8]) = avv;
        *reinterpret_cast<uint4*>(&Bs[arow][seg * 8]) = bvv;
        __syncthreads();
        bf16x8 a0 = *reinterpret_cast<const bf16x8*>(&As[wm * 32      + fr][fs * 8]);
        bf16x8 a1 = *reinterpret_cast<const bf16x8*>(&As[wm * 32 + 16 + fr][fs * 8]);
        bf16x8 b0 = *reinterpret_cast<const bf16x8*>(&Bs[wn * 32      + fr][fs * 8]);
        bf16x8 b1 = *reinterpret_cast<const bf16x8*>(&Bs[wn * 32 + 16 + fr][fs * 8]);
        acc00 = mfma16(a0, b0, acc00);
        acc01 = mfma16(a0, b1, acc01);
        acc10 = mfma16(a1, b0, acc10);
        acc11 = mfma16(a1, b1, acc11);
    }
    const int c0 = n0 + wn * 32 + fr, c1 = c0 + 16;
    #pragma unroll
    for (int mi = 0; mi < 2; ++mi) {
        f32x4 aN0 = mi ? acc10 : acc00;
        f32x4 aN1 = mi ? acc11 : acc01;
        #pragma unroll
        for (int j = 0; j < 4; ++j) {
            int rm = m0 + wm * 32 + mi * 16 + fs * 4 + j;
            zf[(size_t)rm * 256 + c0] = f2b(aN0[j]);
            zf[(size_t)rm * 256 + c1] = f2b(aN1[j]);
        }
    }
}

// ---------------------------------------------------------------------------
// launch (round-13 config + conv mtile swizzle)
// ---------------------------------------------------------------------------
extern "C" void kernel_launch(void* const* d_in, const int* in_sizes, int n_in,
                              void* d_out, int out_size, void* d_ws, size_t ws_size,
                              hipStream_t stream)
{
    const float* x     = (const float*)d_in[0];
    const float* ew[4] = { (const float*)d_in[1],  (const float*)d_in[5],
                           (const float*)d_in[9],  (const float*)d_in[13] };
    const float* eb[4] = { (const float*)d_in[2],  (const float*)d_in[6],
                           (const float*)d_in[10], (const float*)d_in[14] };
    const float* eg[4] = { (const float*)d_in[3],  (const float*)d_in[7],
                           (const float*)d_in[11], (const float*)d_in[15] };
    const float* ebe[4]= { (const float*)d_in[4],  (const float*)d_in[8],
                           (const float*)d_in[12], (const float*)d_in[16] };
    const float* mem   = (const float*)d_in[17];
    const float* dw[4] = { (const float*)d_in[18], (const float*)d_in[22],
                           (const float*)d_in[26], (const float*)d_in[30] };
    const float* db[4] = { (const float*)d_in[19], (const float*)d_in[23],
                           (const float*)d_in[27], (const float*)d_in[31] };
    const float* dg[3] = { (const float*)d_in[20], (const float*)d_in[24],
                           (const float*)d_in[28] };
    const float* dbe[3]= { (const float*)d_in[21], (const float*)d_in[25],
                           (const float*)d_in[29] };

    float* outp  = (float*)d_out;
    float* w_out = (float*)d_out + 2097152;

    char* p = (char*)d_ws;
    auto take = [&](size_t bytes) -> char* {
        char* q = p; p += (bytes + 255) & ~(size_t)255; return q;
    };
    u16* b1   = (u16*)take(50331648ull * 2);
    u16* b2   = (u16*)take(8388608ull * 2);
    u16* b3   = (u16*)take(2097152ull * 2);
    u16* b4   = (u16*)take(262144ull * 2);
    u16* zf   = (u16*)take(262144ull * 2);
    u16* w2   = (u16*)take(331776ull * 2);
    u16* w3   = (u16*)take(884736ull * 2);
    u16* w4   = (u16*)take(1769472ull * 2);
    u16* wd1  = (u16*)take(1769472ull * 2);
    u16* wd2  = (u16*)take(884736ull * 2);
    u16* wd3  = (u16*)take(331776ull * 2);
    u16* wd4  = (u16*)take(2592ull * 2);
    u16* memb = (u16*)take(512000ull * 2);
    u16* memT = (u16*)take(524288ull * 2);
    u16* wb16 = (u16*)take(2097152ull * 2);
    float* P     = (float*)take(16777216ull * 4);
    float* pm    = (float*)take(1048576ull * 4);
    float* pv    = (float*)take(1048576ull * 4);
    float* scb   = (float*)take(7 * 512 * 4);
    float* mnorm = (float*)take(2048 * 4);
    float* znorm = (float*)take(1024 * 4);

    auto SC = [&](int l) { return scb + l * 512; };
    auto SB = [&](int l) { return scb + l * 512 + 256; };

    auto bnc = [&](u16* buf, const float* g, const float* be, int C, int BNl,
                   unsigned total8, int G, int gx, int gy, int gz, int slot, bool apply) {
        bnfin3_k<<<C, 64, 0, stream>>>(pm, pv, g, be, SC(slot), SB(slot),
                                       C, BNl, gx, gy, gz,
                                       (float)C / ((float)total8 * 8.0f));
        if (apply) bnapply_k<<<G, 256, 0, stream>>>(buf, SC(slot), SB(slot), C, total8);
    };

    // ---- weight + memory prep ----
    Rep7 ra;
    ra.src[0]=ew[1]; ra.dst[0]=w2;  ra.co[0]=128; ra.ci[0]=96;
    ra.src[1]=ew[2]; ra.dst[1]=w3;  ra.co[1]=256; ra.ci[1]=128;
    ra.src[2]=ew[3]; ra.dst[2]=w4;  ra.co[2]=256; ra.ci[2]=256;
    ra.src[3]=dw[0]; ra.dst[3]=wd1; ra.co[3]=256; ra.ci[3]=256;
    ra.src[4]=dw[1]; ra.dst[4]=wd2; ra.co[4]=128; ra.ci[4]=256;
    ra.src[5]=dw[2]; ra.dst[5]=wd3; ra.co[5]=96;  ra.ci[5]=128;
    ra.src[6]=dw[3]; ra.dst[6]=wd4; ra.co[6]=1;   ra.ci[6]=96;
    repack7_k<<<dim3(64, 7), 256, 0, stream>>>(ra);
    memprep_k<<<2048, 256, 0, stream>>>(mem, memb, memT, mnorm);

    // ---- encoder ----
    enc1_k<<<dim3(1024, 2), 256, 0, stream>>>(x, ew[0], eb[0], b1);
    bnstat_k<<<768, 256, 0, stream>>>(b1, pm, pv, 96, 6291456u);
    bnfin_k<<<96, 64, 0, stream>>>(pm, pv, eg[0], ebe[0], SC(0), SB(0), 96, 768,
                                   96.0f / (6291456.0f * 8.0f));
    bnapply_k<<<768, 256, 0, stream>>>(b1, SC(0), SB(0), 96, 6291456u);

    conv_mfma3_k<true, 96, 128><<<dim3(512, 1, 1), 512, 0, stream>>>(
        b1, w2, eb[1], b2, pm, pv, 96, 128, 16, 128, 128, 3, 6, 6, 8, 64, 64);
    bnc(b2, eg[1], ebe[1], 128, 128, 1048576u, 512, 512, 1, 1, 1, true);

    conv_mfma3_k<true, 128, 64><<<dim3(64, 4, 1), 512, 0, stream>>>(
        b2, w3, eb[2], b3, pm, pv, 128, 256, 8, 64, 64, 2, 5, 5, 4, 32, 32);
    bnc(b3, eg[2], ebe[2], 256, 64, 262144u, 512, 64, 4, 1, 2, true);

    conv_mfma3_k<true, 128, 64><<<dim3(8, 4, 1), 512, 0, stream>>>(
        b3, w4, eb[3], b4, pm, pv, 256, 256, 4, 32, 32, 1, 4, 4, 2, 16, 16);
    bnc(b4, eg[3], ebe[3], 256, 64, 32768u, 128, 8, 4, 1, 3, true);

    // ---- memory module ----
    znorm_k<<<1024, 64, 0, stream>>>(b4, znorm);
    scores_mfma_k<<<dim3(16, 32), 256, 0, stream>>>(b4, memb, znorm, mnorm, w_out);
    softmax2_k<<<1024, 256, 0, stream>>>(w_out, wb16);
    zhat_mfma_k<<<dim3(16, 4), 256, 0, stream>>>(wb16, memT, zf);

    // ---- decoder ----
    conv_mfma3_k<false, 128, 64><<<dim3(8, 4, 8), 512, 0, stream>>>(
        zf, wd1, db[0], b3, pm, pv, 256, 256, 2, 16, 16, 1, 4, 4, 4, 32, 32);
    bnc(b3, dg[0], dbe[0], 256, 64, 262144u, 512, 8, 4, 8, 4, true);

    conv_mfma3_k<false, 128, 64><<<dim3(64, 2, 8), 512, 0, stream>>>(
        b3, wd2, db[1], b2, pm, pv, 256, 128, 4, 32, 32, 2, 5, 5, 8, 64, 64);
    bnc(b2, dg[1], dbe[1], 128, 64, 1048576u, 512, 64, 2, 8, 5, true);

    conv_mfma3_k<false, 128, 96><<<dim3(512, 1, 8), 512, 0, stream>>>(
        b2, wd3, db[2], b1, pm, pv, 128, 96, 8, 64, 64, 3, 6, 6, 16, 128, 128);
    // BN7 fused into dec4g (reads raw b1 + SC(6)/SB(6)) — finalize only.
    bnc(b1, dg[2], dbe[2], 96, 96, 6291456u, 768, 512, 1, 8, 6, false);

    // ---- dec4: GEMM (fused BN7+LReLU on A) then tap-gather ----
    dec4g_k<<<8192, 256, 0, stream>>>(b1, wd4, SC(6), SB(6), P);
    dec4s_k<<<dim3(4096, 2), 256, 0, stream>>>(P, db[3], outp);
}

// Round 16
// 694.360 us; speedup vs baseline: 1.0191x; 1.0190x over previous
//
#include <hip/hip_runtime.h>
#include <math.h>

typedef unsigned short u16;
typedef __bf16 bf16;
typedef bf16 bf16x8 __attribute__((ext_vector_type(8)));
typedef float f32x4 __attribute__((ext_vector_type(4)));
typedef u16 u16x8 __attribute__((ext_vector_type(8)));

__device__ inline float b2f(u16 u){ unsigned x = ((unsigned)u) << 16; return __builtin_bit_cast(float, x); }
__device__ inline u16 f2b(float f){ bf16 b = (bf16)f; return __builtin_bit_cast(u16, b); }
__device__ inline f32x4 mfma16(bf16x8 a, bf16x8 b, f32x4 c){
    return __builtin_amdgcn_mfma_f32_16x16x32_bf16(a, b, c, 0, 0, 0);
}
__device__ inline void unp8(uint4 v, float* f){
    f[0]=__builtin_bit_cast(float, v.x<<16); f[1]=__builtin_bit_cast(float, v.x&0xffff0000u);
    f[2]=__builtin_bit_cast(float, v.y<<16); f[3]=__builtin_bit_cast(float, v.y&0xffff0000u);
    f[4]=__builtin_bit_cast(float, v.z<<16); f[5]=__builtin_bit_cast(float, v.z&0xffff0000u);
    f[6]=__builtin_bit_cast(float, v.w<<16); f[7]=__builtin_bit_cast(float, v.w&0xffff0000u);
}

// ---------------------------------------------------------------------------
// Merged weight repack: 7 sets, OIDHW fp32 -> [tap][co][ci] bf16. grid (64,7)
// ---------------------------------------------------------------------------
struct Rep7 {
    const float* src[7];
    u16* dst[7];
    int co[7];
    int ci[7];
};
__global__ __launch_bounds__(256) void repack7_k(Rep7 a)
{
    int w = blockIdx.y;
    const float* src = a.src[w]; u16* dst = a.dst[w];
    int Co = a.co[w], Ci = a.ci[w];
    int tot = 27 * Co * Ci;
    for (int e = blockIdx.x * 256 + threadIdx.x; e < tot; e += gridDim.x * 256) {
        int ci = e % Ci; int t2 = e / Ci; int co = t2 % Co; int tp = t2 / Co;
        dst[e] = f2b(src[(size_t)(co * Ci + ci) * 27 + tp]);
    }
}

// ---------------------------------------------------------------------------
// MFMA implicit-GEMM conv3d / convT3d v5 (round-13 proven): 512 thr
// (8 waves, 4M x 2N), BM=128 x BN, K-panel CK per tap. Rotated prefetch:
// loads for panel it+1 issue before panel it's MFMA block.
// Fused BN partial stats in epilogue. grid: (M/128, Co/BN, ISCONV?1:8)
// ---------------------------------------------------------------------------
template<bool ISCONV, int CK, int BN>
__global__ __launch_bounds__(512) void conv_mfma3_k(
    const u16* __restrict__ in, const u16* __restrict__ wt,
    const float* __restrict__ bias, u16* __restrict__ out,
    float* __restrict__ pm, float* __restrict__ pv,
    int Ci, int Co, int Di, int Hi, int Wi,
    int ld, int lh, int lw, int Do, int Ho, int Wo)
{
    constexpr int NK = CK / 32;
    constexpr int NF = BN / 32;
    __shared__ u16 As[128][CK + 8];
    __shared__ u16 Bs[BN][CK + 8];
    const int tid = threadIdx.x;
    const int mtile = blockIdx.x;
    const int co0 = blockIdx.y * BN;
    int pd = 0, ph = 0, pw = 0;
    if (!ISCONV) { int bz = blockIdx.z; pd = bz >> 2; ph = (bz >> 1) & 1; pw = bz & 1; }

    const int arow = tid >> 2, seg = tid & 3;
    int xo, yo, zo, n;
    { int m = mtile * 128 + arow;
      xo = m & ((1 << lw) - 1); m >>= lw;
      yo = m & ((1 << lh) - 1); m >>= lh;
      zo = m & ((1 << ld) - 1); n = m >> ld; }
    const bool isb = arow < BN;

    const int wave = tid >> 6, lane = tid & 63;
    const int wm = wave >> 1, wn = wave & 1;
    const int fr = lane & 15, fs = lane >> 4;

    f32x4 acc[2][NF];
    #pragma unroll
    for (int mf = 0; mf < 2; ++mf)
        #pragma unroll
        for (int nf = 0; nf < NF; ++nf) acc[mf][nf] = f32x4{0,0,0,0};

    const int ntd = ISCONV ? 3 : pd + 1;
    const int nth = ISCONV ? 3 : ph + 1;
    const int ntw = ISCONV ? 3 : pw + 1;
    const int nck = Ci / CK;
    const int T = ntd * nth * ntw * nck;
    const size_t HiWi = (size_t)Hi * Wi;

    int pjd = 0, pjh = 0, pjw = 0, pck = 0;
    uint4 av[NK], bv[NK];

    auto load_panel = [&]() {
        int zi = ISCONV ? 2 * zo + pjd - 1 : zo + (pd ? pjd : 0);
        int wd = ISCONV ? pjd : (pd ? (pjd ? 0 : 2) : 1);
        int yi = ISCONV ? 2 * yo + pjh - 1 : yo + (ph ? pjh : 0);
        int wh = ISCONV ? pjh : (ph ? (pjh ? 0 : 2) : 1);
        int xi = ISCONV ? 2 * xo + pjw - 1 : xo + (pw ? pjw : 0);
        int ww = ISCONV ? pjw : (pw ? (pjw ? 0 : 2) : 1);
        bool va = ((unsigned)zi < (unsigned)Di) && ((unsigned)yi < (unsigned)Hi) &&
                  ((unsigned)xi < (unsigned)Wi);
        size_t abase = 0;
        if (va) abase = (((size_t)(n * Di + zi)) * HiWi + (size_t)yi * Wi + xi) * Ci
                      + (size_t)pck * CK;
        int widx = wd * 9 + wh * 3 + ww;
        size_t bbase = ((size_t)widx * Co + (co0 + arow)) * (size_t)Ci + (size_t)pck * CK;
        #pragma unroll
        for (int k = 0; k < NK; ++k) {
            int col = k * 32 + seg * 8;
            av[k] = va  ? *reinterpret_cast<const uint4*>(in + abase + col) : uint4{0,0,0,0};
            bv[k] = isb ? *reinterpret_cast<const uint4*>(wt + bbase + col) : uint4{0,0,0,0};
        }
        ++pck;
        if (pck == nck) { pck = 0; ++pjw;
            if (pjw == ntw) { pjw = 0; ++pjh;
                if (pjh == nth) { pjh = 0; ++pjd; } } }
    };

    load_panel();
    for (int it = 0; it < T; ++it) {
        __syncthreads();
        #pragma unroll
        for (int k = 0; k < NK; ++k) {
            *reinterpret_cast<uint4*>(&As[arow][k * 32 + seg * 8]) = av[k];
            if (isb) *reinterpret_cast<uint4*>(&Bs[arow][k * 32 + seg * 8]) = bv[k];
        }
        __syncthreads();
        if (it + 1 < T) load_panel();
        #pragma unroll
        for (int k = 0; k < NK; ++k) {
            bf16x8 a0 = *reinterpret_cast<const bf16x8*>(&As[wm * 32      + fr][k * 32 + fs * 8]);
            bf16x8 a1 = *reinterpret_cast<const bf16x8*>(&As[wm * 32 + 16 + fr][k * 32 + fs * 8]);
            #pragma unroll
            for (int nf = 0; nf < NF; ++nf) {
                bf16x8 b = *reinterpret_cast<const bf16x8*>(
                    &Bs[wn * (BN / 2) + nf * 16 + fr][k * 32 + fs * 8]);
                acc[0][nf] = mfma16(a0, b, acc[0][nf]);
                acc[1][nf] = mfma16(a1, b, acc[1][nf]);
            }
        }
    }

    float bi[NF], s[NF], q[NF];
    #pragma unroll
    for (int nf = 0; nf < NF; ++nf) {
        bi[nf] = bias[co0 + wn * (BN / 2) + nf * 16 + fr];
        s[nf] = 0.f; q[nf] = 0.f;
    }
    #pragma unroll
    for (int mf = 0; mf < 2; ++mf) {
        #pragma unroll
        for (int j = 0; j < 4; ++j) {
            int rm = mtile * 128 + wm * 32 + mf * 16 + fs * 4 + j;
            size_t vox;
            if (ISCONV) vox = (size_t)rm;
            else {
                int X = rm & ((1 << lw) - 1); int m2 = rm >> lw;
                int Y = m2 & ((1 << lh) - 1); m2 >>= lh;
                int Z = m2 & ((1 << ld) - 1); int nn = m2 >> ld;
                vox = (((size_t)(nn * Do + (2 * Z + pd))) * Ho + (2 * Y + ph)) * Wo + (2 * X + pw);
            }
            #pragma unroll
            for (int nf = 0; nf < NF; ++nf) {
                float f = acc[mf][nf][j] + bi[nf];
                out[vox * Co + (co0 + wn * (BN / 2) + nf * 16 + fr)] = f2b(f);
                s[nf] += f; q[nf] += f * f;
            }
        }
    }
    __syncthreads();
    float* bnS = reinterpret_cast<float*>(&As[0][0]);   // [BN][16]
    float* bnQ = bnS + BN * 16;
    #pragma unroll
    for (int nf = 0; nf < NF; ++nf) {
        int cl = wn * (BN / 2) + nf * 16 + fr;
        bnS[cl * 16 + wm * 4 + fs] = s[nf];
        bnQ[cl * 16 + wm * 4 + fs] = q[nf];
    }
    __syncthreads();
    if (tid < BN) {
        float S = 0.f, Q = 0.f;
        #pragma unroll
        for (int i = 0; i < 16; ++i) { S += bnS[tid * 16 + i]; Q += bnQ[tid * 16 + i]; }
        int p = blockIdx.x + gridDim.x * (blockIdx.y + gridDim.y * blockIdx.z);
        pm[(size_t)p * BN + tid] = S;
        pv[(size_t)p * BN + tid] = Q;
    }
}

// ---------------------------------------------------------------------------
// enc1 v2 (round-13 proven): weights via block-uniform global reads,
// outputs staged in LDS, coalesced copy-out. grid (1024, 2)
// ---------------------------------------------------------------------------
__global__ __launch_bounds__(256) void enc1_k(
    const float* __restrict__ x, const float* __restrict__ w,
    const float* __restrict__ bias, u16* __restrict__ out)
{
    __shared__ uint4 smem[256 * 13];
    float* Xi = reinterpret_cast<float*>(smem);
    const int tid = threadIdx.x;
    int t = blockIdx.x;
    const int tx = t & 7; t >>= 3;
    const int ty = t & 15; t >>= 4;
    const int tz = t;
    const int n = blockIdx.y;
    const int z0 = tz * 2, y0 = ty * 8, x0 = tx * 16;
    for (int i = tid; i < 2244; i += 256) {
        int fz = i / 561; int r = i - fz * 561; int fy = r / 33; int fx = r - fy * 33;
        int zi = z0 - 1 + fz, yi = 2 * y0 - 1 + fy, xi = 2 * x0 - 1 + fx;
        float v = 0.f;
        if ((unsigned)zi < 16u && (unsigned)yi < 256u && (unsigned)xi < 256u)
            v = x[((size_t)(n * 16 + zi) * 256 + yi) * 256 + xi];
        Xi[i] = v;
    }
    __syncthreads();
    const int lx = tid & 15, ly = (tid >> 4) & 7, lz = tid >> 7;
    float iv[27];
    #pragma unroll
    for (int kd = 0; kd < 3; ++kd)
        #pragma unroll
        for (int kh = 0; kh < 3; ++kh)
            #pragma unroll
            for (int kw = 0; kw < 3; ++kw)
                iv[kd * 9 + kh * 3 + kw] = Xi[(lz + kd) * 561 + (2 * ly + kh) * 33 + (2 * lx + kw)];
    __syncthreads();
    #pragma unroll
    for (int og = 0; og < 12; ++og) {
        u16x8 pk;
        #pragma unroll
        for (int oo = 0; oo < 8; ++oo) {
            int o = og * 8 + oo;
            float a = bias[o];
            #pragma unroll
            for (int tp = 0; tp < 27; ++tp) a += iv[tp] * w[o * 27 + tp];
            pk[oo] = f2b(a);
        }
        smem[tid * 13 + og] = __builtin_bit_cast(uint4, pk);
    }
    __syncthreads();
    #pragma unroll
    for (int it = 0; it < 12; ++it) {
        int i = it * 256 + tid;
        int r = i / 192, j = i - r * 192;
        int rz = r >> 3, ry = r & 7;
        int v = r * 16 + j / 12, c8 = j % 12;
        uint4 val = smem[v * 13 + c8];
        size_t voxbase = ((size_t)(n * 16 + z0 + rz) * 128 + (y0 + ry)) * 128 + x0;
        *reinterpret_cast<uint4*>(out + voxbase * 96 + (size_t)j * 8) = val;
    }
}

// ---------------------------------------------------------------------------
// dec4 phase A (GEMM) with fused BN-apply+LReLU on A. grid 8192.
// ---------------------------------------------------------------------------
__global__ __launch_bounds__(256) void dec4g_k(
    const u16* __restrict__ in, const u16* __restrict__ wt4,
    const float* __restrict__ sc, const float* __restrict__ sb,
    float* __restrict__ P)
{
    __shared__ u16 As[64][120];
    __shared__ u16 Bs[32][120];
    const int tid = threadIdx.x;
    const int vox0 = blockIdx.x << 6;
    for (int i = tid; i < 384; i += 256) {
        int row = i / 12, seg = i - row * 12;
        uint4 v = {0,0,0,0};
        if (row < 27) v = *reinterpret_cast<const uint4*>(wt4 + row * 96 + seg * 8);
        *reinterpret_cast<uint4*>(&Bs[row][seg * 8]) = v;
    }
    for (int i = tid; i < 768; i += 256) {
        int row = i / 12, seg = i - row * 12;
        uint4 v = *reinterpret_cast<const uint4*>(in + (size_t)(vox0 + row) * 96 + seg * 8);
        float f[8]; unp8(v, f);
        int c0 = seg * 8;
        u16x8 pk;
        #pragma unroll
        for (int e = 0; e < 8; ++e) {
            float y = f[e] * sc[c0 + e] + sb[c0 + e];
            y = y >= 0.f ? y : 0.2f * y;
            pk[e] = f2b(y);
        }
        *reinterpret_cast<u16x8*>(&As[row][seg * 8]) = pk;
    }
    __syncthreads();
    const int wave = tid >> 6, lane = tid & 63;
    const int fr = lane & 15, fs = lane >> 4;
    f32x4 acc0 = {0,0,0,0}, acc1 = {0,0,0,0};
    #pragma unroll
    for (int kk = 0; kk < 3; ++kk) {
        bf16x8 a  = *reinterpret_cast<const bf16x8*>(&As[wave * 16 + fr][kk * 32 + fs * 8]);
        bf16x8 b0 = *reinterpret_cast<const bf16x8*>(&Bs[fr     ][kk * 32 + fs * 8]);
        bf16x8 b1 = *reinterpret_cast<const bf16x8*>(&Bs[16 + fr][kk * 32 + fs * 8]);
        acc0 = mfma16(a, b0, acc0);
        acc1 = mfma16(a, b1, acc1);
    }
    #pragma unroll
    for (int j = 0; j < 4; ++j) {
        int vox = vox0 + wave * 16 + fs * 4 + j;
        P[(size_t)vox * 32 + fr]      = acc0[j];
        P[(size_t)vox * 32 + 16 + fr] = acc1[j];
    }
}

// ---------------------------------------------------------------------------
// dec4 phase B (gather). grid (4096, 2).
// ---------------------------------------------------------------------------
__global__ __launch_bounds__(256) void dec4s_k(
    const float* __restrict__ P, const float* __restrict__ bias,
    float* __restrict__ out)
{
    __shared__ float Pl[180 * 33];
    const int tid = threadIdx.x;
    int b = blockIdx.x;
    const int tx = b & 15; b >>= 4;
    const int ty = b & 31; b >>= 5;
    const int tz = b;
    const int n = blockIdx.y;
    const int Z0 = tz * 2, Y0 = ty * 8, X0 = tx * 16;
    const int yi0 = Y0 >> 1, xi0 = X0 >> 1;
    for (int i = tid; i < 5760; i += 256) {
        int row = i >> 5, c = i & 31;
        int dz = row / 45; int r = row - dz * 45; int dy = r / 9; int dx = r - dy * 9;
        int zi = Z0 - 1 + dz, yi = yi0 + dy, xi = xi0 + dx;
        float v = 0.f;
        if (zi >= 0 && zi < 16 && yi < 128 && xi < 128)
            v = P[((size_t)((n * 16 + zi) * 128 + yi) * 128 + xi) * 32 + c];
        Pl[row * 33 + c] = v;
    }
    __syncthreads();
    const int lx = tid & 15, ly = (tid >> 4) & 7, lz = tid >> 7;
    float acc = bias[0];
    #pragma unroll
    for (int qd = 0; qd < 3; ++qd) {
        int t = Z0 + lz + qd - 1;
        if (t < 0 || t >= 16) continue;
        int dz = lz + qd;
        #pragma unroll
        for (int qh = 0; qh < 3; ++qh) {
            int u = ly + qh - 1;
            if (u & 1) continue;
            int dy = u >> 1;
            #pragma unroll
            for (int qw = 0; qw < 3; ++qw) {
                int v = lx + qw - 1;
                if (v & 1) continue;
                int dx = v >> 1;
                int widx = (2 - qd) * 9 + (2 - qh) * 3 + (2 - qw);
                acc += Pl[(dz * 45 + dy * 9 + dx) * 33 + widx];
            }
        }
    }
    out[((size_t)(n * 16 + Z0 + lz) * 256 + (Y0 + ly)) * 256 + (X0 + lx)] = acc;
}

// ---------------------------------------------------------------------------
// BN stats for enc1 output (deterministic two-stage LDS reduction).
// ---------------------------------------------------------------------------
__global__ __launch_bounds__(256) void bnstat_k(
    const u16* __restrict__ a, float* __restrict__ pm, float* __restrict__ pv,
    int C, unsigned total8)
{
    __shared__ float sS[256][8];
    __shared__ float sQ[256][8];
    unsigned g = blockIdx.x * 256 + threadIdx.x;
    unsigned stride = gridDim.x * 256;
    float s[8] = {0,0,0,0,0,0,0,0}, q[8] = {0,0,0,0,0,0,0,0};
    for (unsigned i = g; i < total8; i += stride) {
        uint4 v = *reinterpret_cast<const uint4*>(a + (size_t)i * 8);
        float f[8]; unp8(v, f);
        #pragma unroll
        for (int e = 0; e < 8; ++e) { s[e] += f[e]; q[e] += f[e] * f[e]; }
    }
    #pragma unroll
    for (int e = 0; e < 8; ++e) { sS[threadIdx.x][e] = s[e]; sQ[threadIdx.x][e] = q[e]; }
    __syncthreads();
    int c = threadIdx.x;
    if (c < C) {
        int C8 = C >> 3;
        int B = (int)((blockIdx.x * 2048u) % (unsigned)C);
        int r = c - B; r %= C; if (r < 0) r += C;
        int e = r & 7, t0 = r >> 3;
        float S = 0.f, Q = 0.f;
        for (int tt = t0; tt < 256; tt += C8) { S += sS[tt][e]; Q += sQ[tt][e]; }
        pm[blockIdx.x * C + c] = S;
        pv[blockIdx.x * C + c] = Q;
    }
}

__global__ __launch_bounds__(64) void bnfin_k(
    const float* __restrict__ pm, const float* __restrict__ pv,
    const float* __restrict__ g, const float* __restrict__ be,
    float* __restrict__ sc, float* __restrict__ sb, int C, int G, float invcnt)
{
    int c = blockIdx.x;
    float S = 0.f, Q = 0.f;
    for (int b = threadIdx.x; b < G; b += 64) { S += pm[b * C + c]; Q += pv[b * C + c]; }
    #pragma unroll
    for (int off = 32; off; off >>= 1) {
        S += __shfl_down(S, off, 64);
        Q += __shfl_down(Q, off, 64);
    }
    if (threadIdx.x == 0) {
        float m = S * invcnt;
        float v = Q * invcnt - m * m;
        float s = g[c] * rsqrtf(v + 1e-5f);
        sc[c] = s; sb[c] = be[c] - m * s;
    }
}

__global__ __launch_bounds__(64) void bnfin3_k(
    const float* __restrict__ pm, const float* __restrict__ pv,
    const float* __restrict__ g, const float* __restrict__ be,
    float* __restrict__ sc, float* __restrict__ sb,
    int C, int BNl, int gx, int gy, int gz, float invcnt)
{
    int c = blockIdx.x;
    int cog = c / BNl, cl = c % BNl;
    int tot = gx * gz;
    float S = 0.f, Q = 0.f;
    for (int i = threadIdx.x; i < tot; i += 64) {
        int bx = i % gx, bz = i / gx;
        int p = bx + gx * (cog + gy * bz);
        S += pm[(size_t)p * BNl + cl];
        Q += pv[(size_t)p * BNl + cl];
    }
    #pragma unroll
    for (int off = 32; off; off >>= 1) {
        S += __shfl_down(S, off, 64);
        Q += __shfl_down(Q, off, 64);
    }
    if (threadIdx.x == 0) {
        float m = S * invcnt;
        float v = Q * invcnt - m * m;
        float s = g[c] * rsqrtf(v + 1e-5f);
        sc[c] = s; sb[c] = be[c] - m * s;
    }
}

__global__ __launch_bounds__(256) void bnapply_k(
    u16* __restrict__ a, const float* __restrict__ sc, const float* __restrict__ sb,
    int C, unsigned total8)
{
    unsigned g = blockIdx.x * 256 + threadIdx.x;
    unsigned stride = gridDim.x * 256;
    int c0 = (int)((g * 8u) % (unsigned)C);
    float lsc[8], lsb[8];
    #pragma unroll
    for (int e = 0; e < 8; ++e) { lsc[e] = sc[c0 + e]; lsb[e] = sb[c0 + e]; }
    for (unsigned i = g; i < total8; i += stride) {
        uint4 v = *reinterpret_cast<const uint4*>(a + (size_t)i * 8);
        float f[8]; unp8(v, f);
        u16x8 pk;
        #pragma unroll
        for (int e = 0; e < 8; ++e) {
            float y = f[e] * lsc[e] + lsb[e];
            y = y >= 0.f ? y : 0.2f * y;
            pk[e] = f2b(y);
        }
        *reinterpret_cast<u16x8*>(a + (size_t)i * 8) = pk;
    }
}

// ---------------------------------------------------------------------------
// memprep / znorm / scores / softmax / zhat (verified, unchanged)
// ---------------------------------------------------------------------------
__global__ __launch_bounds__(256) void memprep_k(
    const float* __restrict__ mem, u16* __restrict__ memb, u16* __restrict__ memT,
    float* __restrict__ mnorm)
{
    int k = blockIdx.x, c = threadIdx.x;
    if (k >= 2000) { memT[(size_t)c * 2048 + k] = 0; return; }
    float v = mem[(size_t)k * 256 + c];
    u16 b = f2b(v);
    memb[(size_t)k * 256 + c] = b;
    memT[(size_t)c * 2048 + k] = b;
    float s = v * v;
    #pragma unroll
    for (int off = 32; off; off >>= 1) s += __shfl_down(s, off, 64);
    __shared__ float red[4];
    if ((c & 63) == 0) red[c >> 6] = s;
    __syncthreads();
    if (c == 0) mnorm[k] = sqrtf(red[0] + red[1] + red[2] + red[3]);
}

__global__ __launch_bounds__(64) void znorm_k(
    const u16* __restrict__ z, float* __restrict__ znorm)
{
    int m = blockIdx.x, l = threadIdx.x;
    ushort4 v = *reinterpret_cast<const ushort4*>(z + (size_t)m * 256 + l * 4);
    float a = b2f(v.x), b = b2f(v.y), cc = b2f(v.z), d = b2f(v.w);
    float s = a * a + b * b + cc * cc + d * d;
    #pragma unroll
    for (int off = 32; off; off >>= 1) s += __shfl_down(s, off, 64);
    if (l == 0) znorm[m] = sqrtf(s);
}

__global__ __launch_bounds__(256) void scores_mfma_k(
    const u16* __restrict__ z, const u16* __restrict__ memb,
    const float* __restrict__ znorm, const float* __restrict__ mnorm,
    float* __restrict__ scores)
{
    __shared__ u16 As[64][40];
    __shared__ u16 Bs[64][40];
    const int tid = threadIdx.x;
    const int m0 = blockIdx.x << 6, n0 = blockIdx.y << 6;
    const int arow = tid >> 2, seg = tid & 3;
    const bool bok = (n0 + arow) < 2000;
    const int wave = tid >> 6, lane = tid & 63;
    const int wm = wave >> 1, wn = wave & 1, fr = lane & 15, fs = lane >> 4;
    f32x4 acc00 = {0,0,0,0}, acc01 = {0,0,0,0}, acc10 = {0,0,0,0}, acc11 = {0,0,0,0};
    for (int k0 = 0; k0 < 256; k0 += 32) {
        uint4 avv = *reinterpret_cast<const uint4*>(z + (size_t)(m0 + arow) * 256 + k0 + seg * 8);
        uint4 bvv = {0,0,0,0};
        if (bok) bvv = *reinterpret_cast<const uint4*>(memb + (size_t)(n0 + arow) * 256 + k0 + seg * 8);
        __syncthreads();
        *reinterpret_cast<uint4*>(&As[arow][seg * 8]) = avv;
        *reinterpret_cast<uint4*>(&Bs[arow][seg * 8]) = bvv;
        __syncthreads();
        bf16x8 a0 = *reinterpret_cast<const bf16x8*>(&As[wm * 32      + fr][fs * 8]);
        bf16x8 a1 = *reinterpret_cast<const bf16x8*>(&As[wm * 32 + 16 + fr][fs * 8]);
        bf16x8 b0 = *reinterpret_cast<const bf16x8*>(&Bs[wn * 32      + fr][fs * 8]);
        bf16x8 b1 = *reinterpret_cast<const bf16x8*>(&Bs[wn * 32 + 16 + fr][fs * 8]);
        acc00 = mfma16(a0, b0, acc00);
        acc01 = mfma16(a0, b1, acc01);
        acc10 = mfma16(a1, b0, acc10);
        acc11 = mfma16(a1, b1, acc11);
    }
    const int c0 = n0 + wn * 32 + fr, c1 = c0 + 16;
    float mn0 = (c0 < 2000) ? mnorm[c0] : 1.f;
    float mn1 = (c1 < 2000) ? mnorm[c1] : 1.f;
    #pragma unroll
    for (int mi = 0; mi < 2; ++mi) {
        f32x4 aN0 = mi ? acc10 : acc00;
        f32x4 aN1 = mi ? acc11 : acc01;
        #pragma unroll
        for (int j = 0; j < 4; ++j) {
            int rm = m0 + wm * 32 + mi * 16 + fs * 4 + j;
            float zn = znorm[rm];
            if (c0 < 2000) scores[(size_t)rm * 2000 + c0] = aN0[j] / fmaxf(zn * mn0, 1e-8f);
            if (c1 < 2000) scores[(size_t)rm * 2000 + c1] = aN1[j] / fmaxf(zn * mn1, 1e-8f);
        }
    }
}

__global__ __launch_bounds__(256) void softmax2_k(
    float* __restrict__ w, u16* __restrict__ wb16)
{
    __shared__ float red[4];
    const int m = blockIdx.x, t = threadIdx.x;
    const bool act = t < 250;
    float v[8];
    if (act) {
        float4 p0 = *reinterpret_cast<const float4*>(w + (size_t)m * 2000 + t * 8);
        float4 p1 = *reinterpret_cast<const float4*>(w + (size_t)m * 2000 + t * 8 + 4);
        v[0]=p0.x; v[1]=p0.y; v[2]=p0.z; v[3]=p0.w;
        v[4]=p1.x; v[5]=p1.y; v[6]=p1.z; v[7]=p1.w;
    } else {
        for (int i = 0; i < 8; ++i) v[i] = -1e30f;
    }
    float mx = -1e30f;
    for (int i = 0; i < 8; ++i) mx = fmaxf(mx, v[i]);
    #pragma unroll
    for (int off = 32; off; off >>= 1) mx = fmaxf(mx, __shfl_down(mx, off, 64));
    if ((t & 63) == 0) red[t >> 6] = mx;
    __syncthreads();
    mx = fmaxf(fmaxf(red[0], red[1]), fmaxf(red[2], red[3]));
    __syncthreads();
    float e[8], sm = 0.f;
    for (int i = 0; i < 8; ++i) {
        e[i] = act ? expf(v[i] - mx) : 0.f;
        sm += e[i];
    }
    #pragma unroll
    for (int off = 32; off; off >>= 1) sm += __shfl_down(sm, off, 64);
    if ((t & 63) == 0) red[t >> 6] = sm;
    __syncthreads();
    float inv = 1.0f / (red[0] + red[1] + red[2] + red[3]);
    u16x8 pk = {0,0,0,0,0,0,0,0};
    if (act) {
        float r[8];
        for (int i = 0; i < 8; ++i) { r[i] = e[i] * inv; pk[i] = f2b(r[i]); }
        float4 o0, o1;
        o0.x=r[0]; o0.y=r[1]; o0.z=r[2]; o0.w=r[3];
        o1.x=r[4]; o1.y=r[5]; o1.z=r[6]; o1.w=r[7];
        *reinterpret_cast<float4*>(w + (size_t)m * 2000 + t * 8)     = o0;
        *reinterpret_cast<float4*>(w + (size_t)m * 2000 + t * 8 + 4) = o1;
    }
    *reinterpret_cast<u16x8*>(wb16 + (size_t)m * 2048 + t * 8) = pk;
}

__global__ __launch_bounds__(256) void zhat_mfma_k(
    const u16* __restrict__ wb16, const u16* __restrict__ memT,
    u16* __restrict__ zf)
{
    __shared__ u16 As[64][40];
    __shared__ u16 Bs[64][40];
    const int tid = threadIdx.x;
    const int m0 = blockIdx.x << 6, n0 = blockIdx.y << 6;
    const int arow = tid >> 2, seg = tid & 3;
    const int wave = tid >> 6, lane = tid & 63;
    const int wm = wave >> 1, wn = wave & 1, fr = lane & 15, fs = lane >> 4;
    f32x4 acc00 = {0,0,0,0}, acc01 = {0,0,0,0}, acc10 = {0,0,0,0}, acc11 = {0,0,0,0};
    for (int k0 = 0; k0 < 2048; k0 += 32) {
        uint4 avv = *reinterpret_cast<const uint4*>(wb16 + (size_t)(m0 + arow) * 2048 + k0 + seg * 8);
        uint4 bvv = *reinterpret_cast<const uint4*>(memT + (size_t)(n0 + arow) * 2048 + k0 + seg * 8);
        __syncthreads();
        *reinterpret_cast<uint4*>(&As[arow][seg * 8]) = avv;
        *reinterpret_cast<uint4*>(&Bs[arow][seg * 8]) = bvv;
        __syncthreads();
        bf16x8 a0 = *reinterpret_cast<const bf16x8*>(&As[wm * 32      + fr][fs * 8]);
        bf16x8 a1 = *reinterpret_cast<const bf16x8*>(&As[wm * 32 + 16 + fr][fs * 8]);
        bf16x8 b0 = *reinterpret_cast<const bf16x8*>(&Bs[wn * 32      + fr][fs * 8]);
        bf16x8 b1 = *reinterpret_cast<const bf16x8*>(&Bs[wn * 32 + 16 + fr][fs * 8]);
        acc00 = mfma16(a0, b0, acc00);
        acc01 = mfma16(a0, b1, acc01);
        acc10 = mfma16(a1, b0, acc10);
        acc11 = mfma16(a1, b1, acc11);
    }
    const int c0 = n0 + wn * 32 + fr, c1 = c0 + 16;
    #pragma unroll
    for (int mi = 0; mi < 2; ++mi) {
        f32x4 aN0 = mi ? acc10 : acc00;
        f32x4 aN1 = mi ? acc11 : acc01;
        #pragma unroll
        for (int j = 0; j < 4; ++j) {
            int rm = m0 + wm * 32 + mi * 16 + fs * 4 + j;
            zf[(size_t)rm * 256 + c0] = f2b(aN0[j]);
            zf[(size_t)rm * 256 + c1] = f2b(aN1[j]);
        }
    }
}

// ---------------------------------------------------------------------------
// launch (round-13 exact configuration — best measured: 693 us)
// ---------------------------------------------------------------------------
extern "C" void kernel_launch(void* const* d_in, const int* in_sizes, int n_in,
                              void* d_out, int out_size, void* d_ws, size_t ws_size,
                              hipStream_t stream)
{
    const float* x     = (const float*)d_in[0];
    const float* ew[4] = { (const float*)d_in[1],  (const float*)d_in[5],
                           (const float*)d_in[9],  (const float*)d_in[13] };
    const float* eb[4] = { (const float*)d_in[2],  (const float*)d_in[6],
                           (const float*)d_in[10], (const float*)d_in[14] };
    const float* eg[4] = { (const float*)d_in[3],  (const float*)d_in[7],
                           (const float*)d_in[11], (const float*)d_in[15] };
    const float* ebe[4]= { (const float*)d_in[4],  (const float*)d_in[8],
                           (const float*)d_in[12], (const float*)d_in[16] };
    const float* mem   = (const float*)d_in[17];
    const float* dw[4] = { (const float*)d_in[18], (const float*)d_in[22],
                           (const float*)d_in[26], (const float*)d_in[30] };
    const float* db[4] = { (const float*)d_in[19], (const float*)d_in[23],
                           (const float*)d_in[27], (const float*)d_in[31] };
    const float* dg[3] = { (const float*)d_in[20], (const float*)d_in[24],
                           (const float*)d_in[28] };
    const float* dbe[3]= { (const float*)d_in[21], (const float*)d_in[25],
                           (const float*)d_in[29] };

    float* outp  = (float*)d_out;
    float* w_out = (float*)d_out + 2097152;

    char* p = (char*)d_ws;
    auto take = [&](size_t bytes) -> char* {
        char* q = p; p += (bytes + 255) & ~(size_t)255; return q;
    };
    u16* b1   = (u16*)take(50331648ull * 2);
    u16* b2   = (u16*)take(8388608ull * 2);
    u16* b3   = (u16*)take(2097152ull * 2);
    u16* b4   = (u16*)take(262144ull * 2);
    u16* zf   = (u16*)take(262144ull * 2);
    u16* w2   = (u16*)take(331776ull * 2);
    u16* w3   = (u16*)take(884736ull * 2);
    u16* w4   = (u16*)take(1769472ull * 2);
    u16* wd1  = (u16*)take(1769472ull * 2);
    u16* wd2  = (u16*)take(884736ull * 2);
    u16* wd3  = (u16*)take(331776ull * 2);
    u16* wd4  = (u16*)take(2592ull * 2);
    u16* memb = (u16*)take(512000ull * 2);
    u16* memT = (u16*)take(524288ull * 2);
    u16* wb16 = (u16*)take(2097152ull * 2);
    float* P     = (float*)take(16777216ull * 4);
    float* pm    = (float*)take(1048576ull * 4);
    float* pv    = (float*)take(1048576ull * 4);
    float* scb   = (float*)take(7 * 512 * 4);
    float* mnorm = (float*)take(2048 * 4);
    float* znorm = (float*)take(1024 * 4);

    auto SC = [&](int l) { return scb + l * 512; };
    auto SB = [&](int l) { return scb + l * 512 + 256; };

    auto bnc = [&](u16* buf, const float* g, const float* be, int C, int BNl,
                   unsigned total8, int G, int gx, int gy, int gz, int slot, bool apply) {
        bnfin3_k<<<C, 64, 0, stream>>>(pm, pv, g, be, SC(slot), SB(slot),
                                       C, BNl, gx, gy, gz,
                                       (float)C / ((float)total8 * 8.0f));
        if (apply) bnapply_k<<<G, 256, 0, stream>>>(buf, SC(slot), SB(slot), C, total8);
    };

    // ---- weight + memory prep ----
    Rep7 ra;
    ra.src[0]=ew[1]; ra.dst[0]=w2;  ra.co[0]=128; ra.ci[0]=96;
    ra.src[1]=ew[2]; ra.dst[1]=w3;  ra.co[1]=256; ra.ci[1]=128;
    ra.src[2]=ew[3]; ra.dst[2]=w4;  ra.co[2]=256; ra.ci[2]=256;
    ra.src[3]=dw[0]; ra.dst[3]=wd1; ra.co[3]=256; ra.ci[3]=256;
    ra.src[4]=dw[1]; ra.dst[4]=wd2; ra.co[4]=128; ra.ci[4]=256;
    ra.src[5]=dw[2]; ra.dst[5]=wd3; ra.co[5]=96;  ra.ci[5]=128;
    ra.src[6]=dw[3]; ra.dst[6]=wd4; ra.co[6]=1;   ra.ci[6]=96;
    repack7_k<<<dim3(64, 7), 256, 0, stream>>>(ra);
    memprep_k<<<2048, 256, 0, stream>>>(mem, memb, memT, mnorm);

    // ---- encoder ----
    enc1_k<<<dim3(1024, 2), 256, 0, stream>>>(x, ew[0], eb[0], b1);
    bnstat_k<<<768, 256, 0, stream>>>(b1, pm, pv, 96, 6291456u);
    bnfin_k<<<96, 64, 0, stream>>>(pm, pv, eg[0], ebe[0], SC(0), SB(0), 96, 768,
                                   96.0f / (6291456.0f * 8.0f));
    bnapply_k<<<768, 256, 0, stream>>>(b1, SC(0), SB(0), 96, 6291456u);

    conv_mfma3_k<true, 96, 128><<<dim3(512, 1, 1), 512, 0, stream>>>(
        b1, w2, eb[1], b2, pm, pv, 96, 128, 16, 128, 128, 3, 6, 6, 8, 64, 64);
    bnc(b2, eg[1], ebe[1], 128, 128, 1048576u, 512, 512, 1, 1, 1, true);

    conv_mfma3_k<true, 128, 64><<<dim3(64, 4, 1), 512, 0, stream>>>(
        b2, w3, eb[2], b3, pm, pv, 128, 256, 8, 64, 64, 2, 5, 5, 4, 32, 32);
    bnc(b3, eg[2], ebe[2], 256, 64, 262144u, 512, 64, 4, 1, 2, true);

    conv_mfma3_k<true, 128, 64><<<dim3(8, 4, 1), 512, 0, stream>>>(
        b3, w4, eb[3], b4, pm, pv, 256, 256, 4, 32, 32, 1, 4, 4, 2, 16, 16);
    bnc(b4, eg[3], ebe[3], 256, 64, 32768u, 128, 8, 4, 1, 3, true);

    // ---- memory module ----
    znorm_k<<<1024, 64, 0, stream>>>(b4, znorm);
    scores_mfma_k<<<dim3(16, 32), 256, 0, stream>>>(b4, memb, znorm, mnorm, w_out);
    softmax2_k<<<1024, 256, 0, stream>>>(w_out, wb16);
    zhat_mfma_k<<<dim3(16, 4), 256, 0, stream>>>(wb16, memT, zf);

    // ---- decoder ----
    conv_mfma3_k<false, 128, 64><<<dim3(8, 4, 8), 512, 0, stream>>>(
        zf, wd1, db[0], b3, pm, pv, 256, 256, 2, 16, 16, 1, 4, 4, 4, 32, 32);
    bnc(b3, dg[0], dbe[0], 256, 64, 262144u, 512, 8, 4, 8, 4, true);

    conv_mfma3_k<false, 128, 64><<<dim3(64, 2, 8), 512, 0, stream>>>(
        b3, wd2, db[1], b2, pm, pv, 256, 128, 4, 32, 32, 2, 5, 5, 8, 64, 64);
    bnc(b2, dg[1], dbe[1], 128, 64, 1048576u, 512, 64, 2, 8, 5, true);

    conv_mfma3_k<false, 128, 96><<<dim3(512, 1, 8), 512, 0, stream>>>(
        b2, wd3, db[2], b1, pm, pv, 128, 96, 8, 64, 64, 3, 6, 6, 16, 128, 128);
    // BN7 fused into dec4g (reads raw b1 + SC(6)/SB(6)) — finalize only.
    bnc(b1, dg[2], dbe[2], 96, 96, 6291456u, 768, 512, 1, 8, 6, false);

    // ---- dec4: GEMM (fused BN7+LReLU on A) then tap-gather ----
    dec4g_k<<<8192, 256, 0, stream>>>(b1, wd4, SC(6), SB(6), P);
    dec4s_k<<<dim3(4096, 2), 256, 0, stream>>>(P, db[3], outp);
}

// Round 17
// 683.390 us; speedup vs baseline: 1.0355x; 1.0161x over previous
//
#include <hip/hip_runtime.h>
#include <math.h>

typedef unsigned short u16;
typedef __bf16 bf16;
typedef bf16 bf16x8 __attribute__((ext_vector_type(8)));
typedef float f32x4 __attribute__((ext_vector_type(4)));
typedef u16 u16x8 __attribute__((ext_vector_type(8)));

__device__ inline float b2f(u16 u){ unsigned x = ((unsigned)u) << 16; return __builtin_bit_cast(float, x); }
__device__ inline u16 f2b(float f){ bf16 b = (bf16)f; return __builtin_bit_cast(u16, b); }
__device__ inline f32x4 mfma16(bf16x8 a, bf16x8 b, f32x4 c){
    return __builtin_amdgcn_mfma_f32_16x16x32_bf16(a, b, c, 0, 0, 0);
}
__device__ inline void unp8(uint4 v, float* f){
    f[0]=__builtin_bit_cast(float, v.x<<16); f[1]=__builtin_bit_cast(float, v.x&0xffff0000u);
    f[2]=__builtin_bit_cast(float, v.y<<16); f[3]=__builtin_bit_cast(float, v.y&0xffff0000u);
    f[4]=__builtin_bit_cast(float, v.z<<16); f[5]=__builtin_bit_cast(float, v.z&0xffff0000u);
    f[6]=__builtin_bit_cast(float, v.w<<16); f[7]=__builtin_bit_cast(float, v.w&0xffff0000u);
}

// ---------------------------------------------------------------------------
// Merged weight repack: 7 sets, OIDHW fp32 -> [tap][co][ci] bf16. grid (64,7)
// ---------------------------------------------------------------------------
struct Rep7 {
    const float* src[7];
    u16* dst[7];
    int co[7];
    int ci[7];
};
__global__ __launch_bounds__(256) void repack7_k(Rep7 a)
{
    int w = blockIdx.y;
    const float* src = a.src[w]; u16* dst = a.dst[w];
    int Co = a.co[w], Ci = a.ci[w];
    int tot = 27 * Co * Ci;
    for (int e = blockIdx.x * 256 + threadIdx.x; e < tot; e += gridDim.x * 256) {
        int ci = e % Ci; int t2 = e / Ci; int co = t2 % Co; int tp = t2 / Co;
        dst[e] = f2b(src[(size_t)(co * Ci + ci) * 27 + tp]);
    }
}

// ---------------------------------------------------------------------------
// MFMA implicit-GEMM conv3d / convT3d v6: round-13 v5 structure + optional
// LDS-table BN-apply+LReLU on the A operand at the As-write site (HASBN;
// requires Ci==CK). load_panel stays pure loads (prefetch intact); BN uses
// transient regs only. grid: (M/128, Co/BN, ISCONV?1:8)
// ---------------------------------------------------------------------------
template<bool ISCONV, int CK, int BN, bool HASBN>
__global__ __launch_bounds__(512) void conv_mfma3_k(
    const u16* __restrict__ in, const u16* __restrict__ wt,
    const float* __restrict__ bias, u16* __restrict__ out,
    float* __restrict__ pm, float* __restrict__ pv,
    const float* __restrict__ asc, const float* __restrict__ asb,
    int Ci, int Co, int Di, int Hi, int Wi,
    int ld, int lh, int lw, int Do, int Ho, int Wo)
{
    constexpr int NK = CK / 32;
    constexpr int NF = BN / 32;
    __shared__ u16 As[128][CK + 8];
    __shared__ u16 Bs[BN][CK + 8];
    __shared__ float lscS[HASBN ? CK : 1];
    __shared__ float lsbS[HASBN ? CK : 1];
    const int tid = threadIdx.x;
    const int mtile = blockIdx.x;
    const int co0 = blockIdx.y * BN;
    int pd = 0, ph = 0, pw = 0;
    if (!ISCONV) { int bz = blockIdx.z; pd = bz >> 2; ph = (bz >> 1) & 1; pw = bz & 1; }

    const int arow = tid >> 2, seg = tid & 3;
    int xo, yo, zo, n;
    { int m = mtile * 128 + arow;
      xo = m & ((1 << lw) - 1); m >>= lw;
      yo = m & ((1 << lh) - 1); m >>= lh;
      zo = m & ((1 << ld) - 1); n = m >> ld; }
    const bool isb = arow < BN;

    const int wave = tid >> 6, lane = tid & 63;
    const int wm = wave >> 1, wn = wave & 1;
    const int fr = lane & 15, fs = lane >> 4;

    if (HASBN) {
        if (tid < CK) { lscS[tid] = asc[tid]; lsbS[tid] = asb[tid]; }
        __syncthreads();
    }

    f32x4 acc[2][NF];
    #pragma unroll
    for (int mf = 0; mf < 2; ++mf)
        #pragma unroll
        for (int nf = 0; nf < NF; ++nf) acc[mf][nf] = f32x4{0,0,0,0};

    const int ntd = ISCONV ? 3 : pd + 1;
    const int nth = ISCONV ? 3 : ph + 1;
    const int ntw = ISCONV ? 3 : pw + 1;
    const int nck = Ci / CK;
    const int T = ntd * nth * ntw * nck;
    const size_t HiWi = (size_t)Hi * Wi;

    int pjd = 0, pjh = 0, pjw = 0, pck = 0;
    uint4 av[NK], bv[NK];
    bool stVa = false;          // validity of currently staged A regs

    auto load_panel = [&]() {
        int zi = ISCONV ? 2 * zo + pjd - 1 : zo + (pd ? pjd : 0);
        int wd = ISCONV ? pjd : (pd ? (pjd ? 0 : 2) : 1);
        int yi = ISCONV ? 2 * yo + pjh - 1 : yo + (ph ? pjh : 0);
        int wh = ISCONV ? pjh : (ph ? (pjh ? 0 : 2) : 1);
        int xi = ISCONV ? 2 * xo + pjw - 1 : xo + (pw ? pjw : 0);
        int ww = ISCONV ? pjw : (pw ? (pjw ? 0 : 2) : 1);
        bool va = ((unsigned)zi < (unsigned)Di) && ((unsigned)yi < (unsigned)Hi) &&
                  ((unsigned)xi < (unsigned)Wi);
        size_t abase = 0;
        if (va) abase = (((size_t)(n * Di + zi)) * HiWi + (size_t)yi * Wi + xi) * Ci
                      + (size_t)pck * CK;
        int widx = wd * 9 + wh * 3 + ww;
        size_t bbase = ((size_t)widx * Co + (co0 + arow)) * (size_t)Ci + (size_t)pck * CK;
        #pragma unroll
        for (int k = 0; k < NK; ++k) {
            int col = k * 32 + seg * 8;
            av[k] = va  ? *reinterpret_cast<const uint4*>(in + abase + col) : uint4{0,0,0,0};
            bv[k] = isb ? *reinterpret_cast<const uint4*>(wt + bbase + col) : uint4{0,0,0,0};
        }
        stVa = va;
        ++pck;
        if (pck == nck) { pck = 0; ++pjw;
            if (pjw == ntw) { pjw = 0; ++pjh;
                if (pjh == nth) { pjh = 0; ++pjd; } } }
    };

    load_panel();
    for (int it = 0; it < T; ++it) {
        __syncthreads();
        #pragma unroll
        for (int k = 0; k < NK; ++k) {
            uint4 wv = av[k];
            if (HASBN) {
                if (stVa) {
                    float f[8]; unp8(wv, f);
                    u16x8 pk;
                    #pragma unroll
                    for (int e = 0; e < 8; ++e) {
                        float y = f[e] * lscS[k * 32 + seg * 8 + e]
                                + lsbS[k * 32 + seg * 8 + e];
                        y = y >= 0.f ? y : 0.2f * y;
                        pk[e] = f2b(y);
                    }
                    wv = __builtin_bit_cast(uint4, pk);
                }
            }
            *reinterpret_cast<uint4*>(&As[arow][k * 32 + seg * 8]) = wv;
            if (isb) *reinterpret_cast<uint4*>(&Bs[arow][k * 32 + seg * 8]) = bv[k];
        }
        __syncthreads();
        if (it + 1 < T) load_panel();
        #pragma unroll
        for (int k = 0; k < NK; ++k) {
            bf16x8 a0 = *reinterpret_cast<const bf16x8*>(&As[wm * 32      + fr][k * 32 + fs * 8]);
            bf16x8 a1 = *reinterpret_cast<const bf16x8*>(&As[wm * 32 + 16 + fr][k * 32 + fs * 8]);
            #pragma unroll
            for (int nf = 0; nf < NF; ++nf) {
                bf16x8 b = *reinterpret_cast<const bf16x8*>(
                    &Bs[wn * (BN / 2) + nf * 16 + fr][k * 32 + fs * 8]);
                acc[0][nf] = mfma16(a0, b, acc[0][nf]);
                acc[1][nf] = mfma16(a1, b, acc[1][nf]);
            }
        }
    }

    float bi[NF], s[NF], q[NF];
    #pragma unroll
    for (int nf = 0; nf < NF; ++nf) {
        bi[nf] = bias[co0 + wn * (BN / 2) + nf * 16 + fr];
        s[nf] = 0.f; q[nf] = 0.f;
    }
    #pragma unroll
    for (int mf = 0; mf < 2; ++mf) {
        #pragma unroll
        for (int j = 0; j < 4; ++j) {
            int rm = mtile * 128 + wm * 32 + mf * 16 + fs * 4 + j;
            size_t vox;
            if (ISCONV) vox = (size_t)rm;
            else {
                int X = rm & ((1 << lw) - 1); int m2 = rm >> lw;
                int Y = m2 & ((1 << lh) - 1); m2 >>= lh;
                int Z = m2 & ((1 << ld) - 1); int nn = m2 >> ld;
                vox = (((size_t)(nn * Do + (2 * Z + pd))) * Ho + (2 * Y + ph)) * Wo + (2 * X + pw);
            }
            #pragma unroll
            for (int nf = 0; nf < NF; ++nf) {
                float f = acc[mf][nf][j] + bi[nf];
                out[vox * Co + (co0 + wn * (BN / 2) + nf * 16 + fr)] = f2b(f);
                s[nf] += f; q[nf] += f * f;
            }
        }
    }
    __syncthreads();
    float* bnS = reinterpret_cast<float*>(&As[0][0]);   // [BN][16]
    float* bnQ = bnS + BN * 16;
    #pragma unroll
    for (int nf = 0; nf < NF; ++nf) {
        int cl = wn * (BN / 2) + nf * 16 + fr;
        bnS[cl * 16 + wm * 4 + fs] = s[nf];
        bnQ[cl * 16 + wm * 4 + fs] = q[nf];
    }
    __syncthreads();
    if (tid < BN) {
        float S = 0.f, Q = 0.f;
        #pragma unroll
        for (int i = 0; i < 16; ++i) { S += bnS[tid * 16 + i]; Q += bnQ[tid * 16 + i]; }
        int p = blockIdx.x + gridDim.x * (blockIdx.y + gridDim.y * blockIdx.z);
        pm[(size_t)p * BN + tid] = S;
        pv[(size_t)p * BN + tid] = Q;
    }
}

// ---------------------------------------------------------------------------
// enc1 v2 (round-13 proven): weights via block-uniform global reads,
// outputs staged in LDS, coalesced copy-out. grid (1024, 2)
// ---------------------------------------------------------------------------
__global__ __launch_bounds__(256) void enc1_k(
    const float* __restrict__ x, const float* __restrict__ w,
    const float* __restrict__ bias, u16* __restrict__ out)
{
    __shared__ uint4 smem[256 * 13];
    float* Xi = reinterpret_cast<float*>(smem);
    const int tid = threadIdx.x;
    int t = blockIdx.x;
    const int tx = t & 7; t >>= 3;
    const int ty = t & 15; t >>= 4;
    const int tz = t;
    const int n = blockIdx.y;
    const int z0 = tz * 2, y0 = ty * 8, x0 = tx * 16;
    for (int i = tid; i < 2244; i += 256) {
        int fz = i / 561; int r = i - fz * 561; int fy = r / 33; int fx = r - fy * 33;
        int zi = z0 - 1 + fz, yi = 2 * y0 - 1 + fy, xi = 2 * x0 - 1 + fx;
        float v = 0.f;
        if ((unsigned)zi < 16u && (unsigned)yi < 256u && (unsigned)xi < 256u)
            v = x[((size_t)(n * 16 + zi) * 256 + yi) * 256 + xi];
        Xi[i] = v;
    }
    __syncthreads();
    const int lx = tid & 15, ly = (tid >> 4) & 7, lz = tid >> 7;
    float iv[27];
    #pragma unroll
    for (int kd = 0; kd < 3; ++kd)
        #pragma unroll
        for (int kh = 0; kh < 3; ++kh)
            #pragma unroll
            for (int kw = 0; kw < 3; ++kw)
                iv[kd * 9 + kh * 3 + kw] = Xi[(lz + kd) * 561 + (2 * ly + kh) * 33 + (2 * lx + kw)];
    __syncthreads();
    #pragma unroll
    for (int og = 0; og < 12; ++og) {
        u16x8 pk;
        #pragma unroll
        for (int oo = 0; oo < 8; ++oo) {
            int o = og * 8 + oo;
            float a = bias[o];
            #pragma unroll
            for (int tp = 0; tp < 27; ++tp) a += iv[tp] * w[o * 27 + tp];
            pk[oo] = f2b(a);
        }
        smem[tid * 13 + og] = __builtin_bit_cast(uint4, pk);
    }
    __syncthreads();
    #pragma unroll
    for (int it = 0; it < 12; ++it) {
        int i = it * 256 + tid;
        int r = i / 192, j = i - r * 192;
        int rz = r >> 3, ry = r & 7;
        int v = r * 16 + j / 12, c8 = j % 12;
        uint4 val = smem[v * 13 + c8];
        size_t voxbase = ((size_t)(n * 16 + z0 + rz) * 128 + (y0 + ry)) * 128 + x0;
        *reinterpret_cast<uint4*>(out + voxbase * 96 + (size_t)j * 8) = val;
    }
}

// ---------------------------------------------------------------------------
// dec4 phase A (GEMM) with fused BN-apply+LReLU on A. grid 8192.
// ---------------------------------------------------------------------------
__global__ __launch_bounds__(256) void dec4g_k(
    const u16* __restrict__ in, const u16* __restrict__ wt4,
    const float* __restrict__ sc, const float* __restrict__ sb,
    float* __restrict__ P)
{
    __shared__ u16 As[64][120];
    __shared__ u16 Bs[32][120];
    const int tid = threadIdx.x;
    const int vox0 = blockIdx.x << 6;
    for (int i = tid; i < 384; i += 256) {
        int row = i / 12, seg = i - row * 12;
        uint4 v = {0,0,0,0};
        if (row < 27) v = *reinterpret_cast<const uint4*>(wt4 + row * 96 + seg * 8);
        *reinterpret_cast<uint4*>(&Bs[row][seg * 8]) = v;
    }
    for (int i = tid; i < 768; i += 256) {
        int row = i / 12, seg = i - row * 12;
        uint4 v = *reinterpret_cast<const uint4*>(in + (size_t)(vox0 + row) * 96 + seg * 8);
        float f[8]; unp8(v, f);
        int c0 = seg * 8;
        u16x8 pk;
        #pragma unroll
        for (int e = 0; e < 8; ++e) {
            float y = f[e] * sc[c0 + e] + sb[c0 + e];
            y = y >= 0.f ? y : 0.2f * y;
            pk[e] = f2b(y);
        }
        *reinterpret_cast<u16x8*>(&As[row][seg * 8]) = pk;
    }
    __syncthreads();
    const int wave = tid >> 6, lane = tid & 63;
    const int fr = lane & 15, fs = lane >> 4;
    f32x4 acc0 = {0,0,0,0}, acc1 = {0,0,0,0};
    #pragma unroll
    for (int kk = 0; kk < 3; ++kk) {
        bf16x8 a  = *reinterpret_cast<const bf16x8*>(&As[wave * 16 + fr][kk * 32 + fs * 8]);
        bf16x8 b0 = *reinterpret_cast<const bf16x8*>(&Bs[fr     ][kk * 32 + fs * 8]);
        bf16x8 b1 = *reinterpret_cast<const bf16x8*>(&Bs[16 + fr][kk * 32 + fs * 8]);
        acc0 = mfma16(a, b0, acc0);
        acc1 = mfma16(a, b1, acc1);
    }
    #pragma unroll
    for (int j = 0; j < 4; ++j) {
        int vox = vox0 + wave * 16 + fs * 4 + j;
        P[(size_t)vox * 32 + fr]      = acc0[j];
        P[(size_t)vox * 32 + 16 + fr] = acc1[j];
    }
}

// ---------------------------------------------------------------------------
// dec4 phase B (gather). grid (4096, 2).
// ---------------------------------------------------------------------------
__global__ __launch_bounds__(256) void dec4s_k(
    const float* __restrict__ P, const float* __restrict__ bias,
    float* __restrict__ out)
{
    __shared__ float Pl[180 * 33];
    const int tid = threadIdx.x;
    int b = blockIdx.x;
    const int tx = b & 15; b >>= 4;
    const int ty = b & 31; b >>= 5;
    const int tz = b;
    const int n = blockIdx.y;
    const int Z0 = tz * 2, Y0 = ty * 8, X0 = tx * 16;
    const int yi0 = Y0 >> 1, xi0 = X0 >> 1;
    for (int i = tid; i < 5760; i += 256) {
        int row = i >> 5, c = i & 31;
        int dz = row / 45; int r = row - dz * 45; int dy = r / 9; int dx = r - dy * 9;
        int zi = Z0 - 1 + dz, yi = yi0 + dy, xi = xi0 + dx;
        float v = 0.f;
        if (zi >= 0 && zi < 16 && yi < 128 && xi < 128)
            v = P[((size_t)((n * 16 + zi) * 128 + yi) * 128 + xi) * 32 + c];
        Pl[row * 33 + c] = v;
    }
    __syncthreads();
    const int lx = tid & 15, ly = (tid >> 4) & 7, lz = tid >> 7;
    float acc = bias[0];
    #pragma unroll
    for (int qd = 0; qd < 3; ++qd) {
        int t = Z0 + lz + qd - 1;
        if (t < 0 || t >= 16) continue;
        int dz = lz + qd;
        #pragma unroll
        for (int qh = 0; qh < 3; ++qh) {
            int u = ly + qh - 1;
            if (u & 1) continue;
            int dy = u >> 1;
            #pragma unroll
            for (int qw = 0; qw < 3; ++qw) {
                int v = lx + qw - 1;
                if (v & 1) continue;
                int dx = v >> 1;
                int widx = (2 - qd) * 9 + (2 - qh) * 3 + (2 - qw);
                acc += Pl[(dz * 45 + dy * 9 + dx) * 33 + widx];
            }
        }
    }
    out[((size_t)(n * 16 + Z0 + lz) * 256 + (Y0 + ly)) * 256 + (X0 + lx)] = acc;
}

// ---------------------------------------------------------------------------
// BN stats for enc1 output (deterministic two-stage LDS reduction).
// ---------------------------------------------------------------------------
__global__ __launch_bounds__(256) void bnstat_k(
    const u16* __restrict__ a, float* __restrict__ pm, float* __restrict__ pv,
    int C, unsigned total8)
{
    __shared__ float sS[256][8];
    __shared__ float sQ[256][8];
    unsigned g = blockIdx.x * 256 + threadIdx.x;
    unsigned stride = gridDim.x * 256;
    float s[8] = {0,0,0,0,0,0,0,0}, q[8] = {0,0,0,0,0,0,0,0};
    for (unsigned i = g; i < total8; i += stride) {
        uint4 v = *reinterpret_cast<const uint4*>(a + (size_t)i * 8);
        float f[8]; unp8(v, f);
        #pragma unroll
        for (int e = 0; e < 8; ++e) { s[e] += f[e]; q[e] += f[e] * f[e]; }
    }
    #pragma unroll
    for (int e = 0; e < 8; ++e) { sS[threadIdx.x][e] = s[e]; sQ[threadIdx.x][e] = q[e]; }
    __syncthreads();
    int c = threadIdx.x;
    if (c < C) {
        int C8 = C >> 3;
        int B = (int)((blockIdx.x * 2048u) % (unsigned)C);
        int r = c - B; r %= C; if (r < 0) r += C;
        int e = r & 7, t0 = r >> 3;
        float S = 0.f, Q = 0.f;
        for (int tt = t0; tt < 256; tt += C8) { S += sS[tt][e]; Q += sQ[tt][e]; }
        pm[blockIdx.x * C + c] = S;
        pv[blockIdx.x * C + c] = Q;
    }
}

__global__ __launch_bounds__(64) void bnfin_k(
    const float* __restrict__ pm, const float* __restrict__ pv,
    const float* __restrict__ g, const float* __restrict__ be,
    float* __restrict__ sc, float* __restrict__ sb, int C, int G, float invcnt)
{
    int c = blockIdx.x;
    float S = 0.f, Q = 0.f;
    for (int b = threadIdx.x; b < G; b += 64) { S += pm[b * C + c]; Q += pv[b * C + c]; }
    #pragma unroll
    for (int off = 32; off; off >>= 1) {
        S += __shfl_down(S, off, 64);
        Q += __shfl_down(Q, off, 64);
    }
    if (threadIdx.x == 0) {
        float m = S * invcnt;
        float v = Q * invcnt - m * m;
        float s = g[c] * rsqrtf(v + 1e-5f);
        sc[c] = s; sb[c] = be[c] - m * s;
    }
}

__global__ __launch_bounds__(64) void bnfin3_k(
    const float* __restrict__ pm, const float* __restrict__ pv,
    const float* __restrict__ g, const float* __restrict__ be,
    float* __restrict__ sc, float* __restrict__ sb,
    int C, int BNl, int gx, int gy, int gz, float invcnt)
{
    int c = blockIdx.x;
    int cog = c / BNl, cl = c % BNl;
    int tot = gx * gz;
    float S = 0.f, Q = 0.f;
    for (int i = threadIdx.x; i < tot; i += 64) {
        int bx = i % gx, bz = i / gx;
        int p = bx + gx * (cog + gy * bz);
        S += pm[(size_t)p * BNl + cl];
        Q += pv[(size_t)p * BNl + cl];
    }
    #pragma unroll
    for (int off = 32; off; off >>= 1) {
        S += __shfl_down(S, off, 64);
        Q += __shfl_down(Q, off, 64);
    }
    if (threadIdx.x == 0) {
        float m = S * invcnt;
        float v = Q * invcnt - m * m;
        float s = g[c] * rsqrtf(v + 1e-5f);
        sc[c] = s; sb[c] = be[c] - m * s;
    }
}

__global__ __launch_bounds__(256) void bnapply_k(
    u16* __restrict__ a, const float* __restrict__ sc, const float* __restrict__ sb,
    int C, unsigned total8)
{
    unsigned g = blockIdx.x * 256 + threadIdx.x;
    unsigned stride = gridDim.x * 256;
    int c0 = (int)((g * 8u) % (unsigned)C);
    float lsc[8], lsb[8];
    #pragma unroll
    for (int e = 0; e < 8; ++e) { lsc[e] = sc[c0 + e]; lsb[e] = sb[c0 + e]; }
    for (unsigned i = g; i < total8; i += stride) {
        uint4 v = *reinterpret_cast<const uint4*>(a + (size_t)i * 8);
        float f[8]; unp8(v, f);
        u16x8 pk;
        #pragma unroll
        for (int e = 0; e < 8; ++e) {
            float y = f[e] * lsc[e] + lsb[e];
            y = y >= 0.f ? y : 0.2f * y;
            pk[e] = f2b(y);
        }
        *reinterpret_cast<u16x8*>(a + (size_t)i * 8) = pk;
    }
}

// ---------------------------------------------------------------------------
// memprep / znorm / scores / softmax / zhat (verified, unchanged)
// ---------------------------------------------------------------------------
__global__ __launch_bounds__(256) void memprep_k(
    const float* __restrict__ mem, u16* __restrict__ memb, u16* __restrict__ memT,
    float* __restrict__ mnorm)
{
    int k = blockIdx.x, c = threadIdx.x;
    if (k >= 2000) { memT[(size_t)c * 2048 + k] = 0; return; }
    float v = mem[(size_t)k * 256 + c];
    u16 b = f2b(v);
    memb[(size_t)k * 256 + c] = b;
    memT[(size_t)c * 2048 + k] = b;
    float s = v * v;
    #pragma unroll
    for (int off = 32; off; off >>= 1) s += __shfl_down(s, off, 64);
    __shared__ float red[4];
    if ((c & 63) == 0) red[c >> 6] = s;
    __syncthreads();
    if (c == 0) mnorm[k] = sqrtf(red[0] + red[1] + red[2] + red[3]);
}

__global__ __launch_bounds__(64) void znorm_k(
    const u16* __restrict__ z, float* __restrict__ znorm)
{
    int m = blockIdx.x, l = threadIdx.x;
    ushort4 v = *reinterpret_cast<const ushort4*>(z + (size_t)m * 256 + l * 4);
    float a = b2f(v.x), b = b2f(v.y), cc = b2f(v.z), d = b2f(v.w);
    float s = a * a + b * b + cc * cc + d * d;
    #pragma unroll
    for (int off = 32; off; off >>= 1) s += __shfl_down(s, off, 64);
    if (l == 0) znorm[m] = sqrtf(s);
}

__global__ __launch_bounds__(256) void scores_mfma_k(
    const u16* __restrict__ z, const u16* __restrict__ memb,
    const float* __restrict__ znorm, const float* __restrict__ mnorm,
    float* __restrict__ scores)
{
    __shared__ u16 As[64][40];
    __shared__ u16 Bs[64][40];
    const int tid = threadIdx.x;
    const int m0 = blockIdx.x << 6, n0 = blockIdx.y << 6;
    const int arow = tid >> 2, seg = tid & 3;
    const bool bok = (n0 + arow) < 2000;
    const int wave = tid >> 6, lane = tid & 63;
    const int wm = wave >> 1, wn = wave & 1, fr = lane & 15, fs = lane >> 4;
    f32x4 acc00 = {0,0,0,0}, acc01 = {0,0,0,0}, acc10 = {0,0,0,0}, acc11 = {0,0,0,0};
    for (int k0 = 0; k0 < 256; k0 += 32) {
        uint4 avv = *reinterpret_cast<const uint4*>(z + (size_t)(m0 + arow) * 256 + k0 + seg * 8);
        uint4 bvv = {0,0,0,0};
        if (bok) bvv = *reinterpret_cast<const uint4*>(memb + (size_t)(n0 + arow) * 256 + k0 + seg * 8);
        __syncthreads();
        *reinterpret_cast<uint4*>(&As[arow][seg * 8]) = avv;
        *reinterpret_cast<uint4*>(&Bs[arow][seg * 8]) = bvv;
        __syncthreads();
        bf16x8 a0 = *reinterpret_cast<const bf16x8*>(&As[wm * 32      + fr][fs * 8]);
        bf16x8 a1 = *reinterpret_cast<const bf16x8*>(&As[wm * 32 + 16 + fr][fs * 8]);
        bf16x8 b0 = *reinterpret_cast<const bf16x8*>(&Bs[wn * 32      + fr][fs * 8]);
        bf16x8 b1 = *reinterpret_cast<const bf16x8*>(&Bs[wn * 32 + 16 + fr][fs * 8]);
        acc00 = mfma16(a0, b0, acc00);
        acc01 = mfma16(a0, b1, acc01);
        acc10 = mfma16(a1, b0, acc10);
        acc11 = mfma16(a1, b1, acc11);
    }
    const int c0 = n0 + wn * 32 + fr, c1 = c0 + 16;
    float mn0 = (c0 < 2000) ? mnorm[c0] : 1.f;
    float mn1 = (c1 < 2000) ? mnorm[c1] : 1.f;
    #pragma unroll
    for (int mi = 0; mi < 2; ++mi) {
        f32x4 aN0 = mi ? acc10 : acc00;
        f32x4 aN1 = mi ? acc11 : acc01;
        #pragma unroll
        for (int j = 0; j < 4; ++j) {
            int rm = m0 + wm * 32 + mi * 16 + fs * 4 + j;
            float zn = znorm[rm];
            if (c0 < 2000) scores[(size_t)rm * 2000 + c0] = aN0[j] / fmaxf(zn * mn0, 1e-8f);
            if (c1 < 2000) scores[(size_t)rm * 2000 + c1] = aN1[j] / fmaxf(zn * mn1, 1e-8f);
        }
    }
}

__global__ __launch_bounds__(256) void softmax2_k(
    float* __restrict__ w, u16* __restrict__ wb16)
{
    __shared__ float red[4];
    const int m = blockIdx.x, t = threadIdx.x;
    const bool act = t < 250;
    float v[8];
    if (act) {
        float4 p0 = *reinterpret_cast<const float4*>(w + (size_t)m * 2000 + t * 8);
        float4 p1 = *reinterpret_cast<const float4*>(w + (size_t)m * 2000 + t * 8 + 4);
        v[0]=p0.x; v[1]=p0.y; v[2]=p0.z; v[3]=p0.w;
        v[4]=p1.x; v[5]=p1.y; v[6]=p1.z; v[7]=p1.w;
    } else {
        for (int i = 0; i < 8; ++i) v[i] = -1e30f;
    }
    float mx = -1e30f;
    for (int i = 0; i < 8; ++i) mx = fmaxf(mx, v[i]);
    #pragma unroll
    for (int off = 32; off; off >>= 1) mx = fmaxf(mx, __shfl_down(mx, off, 64));
    if ((t & 63) == 0) red[t >> 6] = mx;
    __syncthreads();
    mx = fmaxf(fmaxf(red[0], red[1]), fmaxf(red[2], red[3]));
    __syncthreads();
    float e[8], sm = 0.f;
    for (int i = 0; i < 8; ++i) {
        e[i] = act ? expf(v[i] - mx) : 0.f;
        sm += e[i];
    }
    #pragma unroll
    for (int off = 32; off; off >>= 1) sm += __shfl_down(sm, off, 64);
    if ((t & 63) == 0) red[t >> 6] = sm;
    __syncthreads();
    float inv = 1.0f / (red[0] + red[1] + red[2] + red[3]);
    u16x8 pk = {0,0,0,0,0,0,0,0};
    if (act) {
        float r[8];
        for (int i = 0; i < 8; ++i) { r[i] = e[i] * inv; pk[i] = f2b(r[i]); }
        float4 o0, o1;
        o0.x=r[0]; o0.y=r[1]; o0.z=r[2]; o0.w=r[3];
        o1.x=r[4]; o1.y=r[5]; o1.z=r[6]; o1.w=r[7];
        *reinterpret_cast<float4*>(w + (size_t)m * 2000 + t * 8)     = o0;
        *reinterpret_cast<float4*>(w + (size_t)m * 2000 + t * 8 + 4) = o1;
    }
    *reinterpret_cast<u16x8*>(wb16 + (size_t)m * 2048 + t * 8) = pk;
}

__global__ __launch_bounds__(256) void zhat_mfma_k(
    const u16* __restrict__ wb16, const u16* __restrict__ memT,
    u16* __restrict__ zf)
{
    __shared__ u16 As[64][40];
    __shared__ u16 Bs[64][40];
    const int tid = threadIdx.x;
    const int m0 = blockIdx.x << 6, n0 = blockIdx.y << 6;
    const int arow = tid >> 2, seg = tid & 3;
    const int wave = tid >> 6, lane = tid & 63;
    const int wm = wave >> 1, wn = wave & 1, fr = lane & 15, fs = lane >> 4;
    f32x4 acc00 = {0,0,0,0}, acc01 = {0,0,0,0}, acc10 = {0,0,0,0}, acc11 = {0,0,0,0};
    for (int k0 = 0; k0 < 2048; k0 += 32) {
        uint4 avv = *reinterpret_cast<const uint4*>(wb16 + (size_t)(m0 + arow) * 2048 + k0 + seg * 8);
        uint4 bvv = *reinterpret_cast<const uint4*>(memT + (size_t)(n0 + arow) * 2048 + k0 + seg * 8);
        __syncthreads();
        *reinterpret_cast<uint4*>(&As[arow][seg * 8]) = avv;
        *reinterpret_cast<uint4*>(&Bs[arow][seg * 8]) = bvv;
        __syncthreads();
        bf16x8 a0 = *reinterpret_cast<const bf16x8*>(&As[wm * 32      + fr][fs * 8]);
        bf16x8 a1 = *reinterpret_cast<const bf16x8*>(&As[wm * 32 + 16 + fr][fs * 8]);
        bf16x8 b0 = *reinterpret_cast<const bf16x8*>(&Bs[wn * 32      + fr][fs * 8]);
        bf16x8 b1 = *reinterpret_cast<const bf16x8*>(&Bs[wn * 32 + 16 + fr][fs * 8]);
        acc00 = mfma16(a0, b0, acc00);
        acc01 = mfma16(a0, b1, acc01);
        acc10 = mfma16(a1, b0, acc10);
        acc11 = mfma16(a1, b1, acc11);
    }
    const int c0 = n0 + wn * 32 + fr, c1 = c0 + 16;
    #pragma unroll
    for (int mi = 0; mi < 2; ++mi) {
        f32x4 aN0 = mi ? acc10 : acc00;
        f32x4 aN1 = mi ? acc11 : acc01;
        #pragma unroll
        for (int j = 0; j < 4; ++j) {
            int rm = m0 + wm * 32 + mi * 16 + fs * 4 + j;
            zf[(size_t)rm * 256 + c0] = f2b(aN0[j]);
            zf[(size_t)rm * 256 + c1] = f2b(aN1[j]);
        }
    }
}

// ---------------------------------------------------------------------------
// launch (round-13 config + BN1 fused into enc2 via LDS tables)
// ---------------------------------------------------------------------------
extern "C" void kernel_launch(void* const* d_in, const int* in_sizes, int n_in,
                              void* d_out, int out_size, void* d_ws, size_t ws_size,
                              hipStream_t stream)
{
    const float* x     = (const float*)d_in[0];
    const float* ew[4] = { (const float*)d_in[1],  (const float*)d_in[5],
                           (const float*)d_in[9],  (const float*)d_in[13] };
    const float* eb[4] = { (const float*)d_in[2],  (const float*)d_in[6],
                           (const float*)d_in[10], (const float*)d_in[14] };
    const float* eg[4] = { (const float*)d_in[3],  (const float*)d_in[7],
                           (const float*)d_in[11], (const float*)d_in[15] };
    const float* ebe[4]= { (const float*)d_in[4],  (const float*)d_in[8],
                           (const float*)d_in[12], (const float*)d_in[16] };
    const float* mem   = (const float*)d_in[17];
    const float* dw[4] = { (const float*)d_in[18], (const float*)d_in[22],
                           (const float*)d_in[26], (const float*)d_in[30] };
    const float* db[4] = { (const float*)d_in[19], (const float*)d_in[23],
                           (const float*)d_in[27], (const float*)d_in[31] };
    const float* dg[3] = { (const float*)d_in[20], (const float*)d_in[24],
                           (const float*)d_in[28] };
    const float* dbe[3]= { (const float*)d_in[21], (const float*)d_in[25],
                           (const float*)d_in[29] };

    float* outp  = (float*)d_out;
    float* w_out = (float*)d_out + 2097152;

    char* p = (char*)d_ws;
    auto take = [&](size_t bytes) -> char* {
        char* q = p; p += (bytes + 255) & ~(size_t)255; return q;
    };
    u16* b1   = (u16*)take(50331648ull * 2);
    u16* b2   = (u16*)take(8388608ull * 2);
    u16* b3   = (u16*)take(2097152ull * 2);
    u16* b4   = (u16*)take(262144ull * 2);
    u16* zf   = (u16*)take(262144ull * 2);
    u16* w2   = (u16*)take(331776ull * 2);
    u16* w3   = (u16*)take(884736ull * 2);
    u16* w4   = (u16*)take(1769472ull * 2);
    u16* wd1  = (u16*)take(1769472ull * 2);
    u16* wd2  = (u16*)take(884736ull * 2);
    u16* wd3  = (u16*)take(331776ull * 2);
    u16* wd4  = (u16*)take(2592ull * 2);
    u16* memb = (u16*)take(512000ull * 2);
    u16* memT = (u16*)take(524288ull * 2);
    u16* wb16 = (u16*)take(2097152ull * 2);
    float* P     = (float*)take(16777216ull * 4);
    float* pm    = (float*)take(1048576ull * 4);
    float* pv    = (float*)take(1048576ull * 4);
    float* scb   = (float*)take(7 * 512 * 4);
    float* mnorm = (float*)take(2048 * 4);
    float* znorm = (float*)take(1024 * 4);

    auto SC = [&](int l) { return scb + l * 512; };
    auto SB = [&](int l) { return scb + l * 512 + 256; };

    auto bnc = [&](u16* buf, const float* g, const float* be, int C, int BNl,
                   unsigned total8, int G, int gx, int gy, int gz, int slot, bool apply) {
        bnfin3_k<<<C, 64, 0, stream>>>(pm, pv, g, be, SC(slot), SB(slot),
                                       C, BNl, gx, gy, gz,
                                       (float)C / ((float)total8 * 8.0f));
        if (apply) bnapply_k<<<G, 256, 0, stream>>>(buf, SC(slot), SB(slot), C, total8);
    };

    // ---- weight + memory prep ----
    Rep7 ra;
    ra.src[0]=ew[1]; ra.dst[0]=w2;  ra.co[0]=128; ra.ci[0]=96;
    ra.src[1]=ew[2]; ra.dst[1]=w3;  ra.co[1]=256; ra.ci[1]=128;
    ra.src[2]=ew[3]; ra.dst[2]=w4;  ra.co[2]=256; ra.ci[2]=256;
    ra.src[3]=dw[0]; ra.dst[3]=wd1; ra.co[3]=256; ra.ci[3]=256;
    ra.src[4]=dw[1]; ra.dst[4]=wd2; ra.co[4]=128; ra.ci[4]=256;
    ra.src[5]=dw[2]; ra.dst[5]=wd3; ra.co[5]=96;  ra.ci[5]=128;
    ra.src[6]=dw[3]; ra.dst[6]=wd4; ra.co[6]=1;   ra.ci[6]=96;
    repack7_k<<<dim3(64, 7), 256, 0, stream>>>(ra);
    memprep_k<<<2048, 256, 0, stream>>>(mem, memb, memT, mnorm);

    // ---- encoder ----
    enc1_k<<<dim3(1024, 2), 256, 0, stream>>>(x, ew[0], eb[0], b1);
    bnstat_k<<<768, 256, 0, stream>>>(b1, pm, pv, 96, 6291456u);
    bnfin_k<<<96, 64, 0, stream>>>(pm, pv, eg[0], ebe[0], SC(0), SB(0), 96, 768,
                                   96.0f / (6291456.0f * 8.0f));
    // BN1 fused into enc2's A-staging via LDS tables (b1 stays raw; only enc2 reads it)

    conv_mfma3_k<true, 96, 128, true><<<dim3(512, 1, 1), 512, 0, stream>>>(
        b1, w2, eb[1], b2, pm, pv, SC(0), SB(0),
        96, 128, 16, 128, 128, 3, 6, 6, 8, 64, 64);
    bnc(b2, eg[1], ebe[1], 128, 128, 1048576u, 512, 512, 1, 1, 1, true);

    conv_mfma3_k<true, 128, 64, false><<<dim3(64, 4, 1), 512, 0, stream>>>(
        b2, w3, eb[2], b3, pm, pv, nullptr, nullptr,
        128, 256, 8, 64, 64, 2, 5, 5, 4, 32, 32);
    bnc(b3, eg[2], ebe[2], 256, 64, 262144u, 512, 64, 4, 1, 2, true);

    conv_mfma3_k<true, 128, 64, false><<<dim3(8, 4, 1), 512, 0, stream>>>(
        b3, w4, eb[3], b4, pm, pv, nullptr, nullptr,
        256, 256, 4, 32, 32, 1, 4, 4, 2, 16, 16);
    bnc(b4, eg[3], ebe[3], 256, 64, 32768u, 128, 8, 4, 1, 3, true);

    // ---- memory module ----
    znorm_k<<<1024, 64, 0, stream>>>(b4, znorm);
    scores_mfma_k<<<dim3(16, 32), 256, 0, stream>>>(b4, memb, znorm, mnorm, w_out);
    softmax2_k<<<1024, 256, 0, stream>>>(w_out, wb16);
    zhat_mfma_k<<<dim3(16, 4), 256, 0, stream>>>(wb16, memT, zf);

    // ---- decoder ----
    conv_mfma3_k<false, 128, 64, false><<<dim3(8, 4, 8), 512, 0, stream>>>(
        zf, wd1, db[0], b3, pm, pv, nullptr, nullptr,
        256, 256, 2, 16, 16, 1, 4, 4, 4, 32, 32);
    bnc(b3, dg[0], dbe[0], 256, 64, 262144u, 512, 8, 4, 8, 4, true);

    conv_mfma3_k<false, 128, 64, false><<<dim3(64, 2, 8), 512, 0, stream>>>(
        b3, wd2, db[1], b2, pm, pv, nullptr, nullptr,
        256, 128, 4, 32, 32, 2, 5, 5, 8, 64, 64);
    bnc(b2, dg[1], dbe[1], 128, 64, 1048576u, 512, 64, 2, 8, 5, true);

    conv_mfma3_k<false, 128, 96, false><<<dim3(512, 1, 8), 512, 0, stream>>>(
        b2, wd3, db[2], b1, pm, pv, nullptr, nullptr,
        128, 96, 8, 64, 64, 3, 6, 6, 16, 128, 128);
    // BN7 fused into dec4g (reads raw b1 + SC(6)/SB(6)) — finalize only.
    bnc(b1, dg[2], dbe[2], 96, 96, 6291456u, 768, 512, 1, 8, 6, false);

    // ---- dec4: GEMM (fused BN7+LReLU on A) then tap-gather ----
    dec4g_k<<<8192, 256, 0, stream>>>(b1, wd4, SC(6), SB(6), P);
    dec4s_k<<<dim3(4096, 2), 256, 0, stream>>>(P, db[3], outp);
}